// Round 10
// baseline (1020.417 us; speedup 1.0000x reference)
//
#include <hip/hip_runtime.h>

typedef unsigned short u16;
typedef __attribute__((ext_vector_type(8))) short  vbf8;   // 8 bf16 (4 VGPRs)
typedef __attribute__((ext_vector_type(4))) float  vf4;    // 4 f32 acc

#define B_   128
#define N_   388
#define NT   128
#define NS   260
#define C_   768
#define H_   12
#define D_   64
#define K3   2304   // 3*C

#define QKV_LEN  114425856ll   // 49664*2304  (bf16 ws)
#define KSM_LEN  25559040ll    // 33280*768
#define CAT_LEN  38141952ll    // 49664*768
#define MEM_LEN  6291456ll     // 128*12*64*64 (f32, in d_out)

#define SPS  288               // sigmaT/wT row stride (keys padded 260->288)
#define SWT_LEN 28311552ll     // 1536*64*288

// bf16 weights: [qkv_w | memk_w | memv_w | proj_w]
#define WOFF_QKV  0ll
#define WOFF_MEMK 1769472ll
#define WOFF_MEMV 2359296ll
#define WOFF_PROJ 2949120ll
#define WTOT     3538944ll
__device__ __align__(16) u16 g_wbf[3538944];

__device__ __forceinline__ float bf2f(u16 u) {
    union { unsigned int i; float f; } v; v.i = ((unsigned int)u) << 16; return v.f;
}
__device__ __forceinline__ u16 f2bf(float f) {
    union { float f; unsigned int i; } v; v.f = f;
    unsigned int r = v.i + 0x7fffu + ((v.i >> 16) & 1u);
    return (u16)(r >> 16);
}
__device__ __forceinline__ float elu1(float x) { return x > 0.f ? x + 1.f : __expf(x); }

__device__ __forceinline__ void gload_lds16(const u16* g, u16* l) {
    __builtin_amdgcn_global_load_lds(
        (const __attribute__((address_space(1))) unsigned int*)g,
        (__attribute__((address_space(3))) unsigned int*)l, 16, 0, 0);
}

// ---------------------------------------------------------------------------
// f32 -> bf16 converters
// ---------------------------------------------------------------------------
__global__ __launch_bounds__(256) void convert_bf16(
    const float* __restrict__ src, u16* __restrict__ dst, long long n)
{
    long long i0 = ((long long)blockIdx.x * 256 + threadIdx.x) * 8;
    long long stride = (long long)gridDim.x * 256 * 8;
    for (long long i = i0; i < n; i += stride) {
        float4 a = *(const float4*)(src + i);
        float4 b = *(const float4*)(src + i + 4);
        ushort4 u1; u1.x = f2bf(a.x); u1.y = f2bf(a.y); u1.z = f2bf(a.z); u1.w = f2bf(a.w);
        ushort4 u2; u2.x = f2bf(b.x); u2.y = f2bf(b.y); u2.z = f2bf(b.z); u2.w = f2bf(b.w);
        *(ushort4*)(dst + i)     = u1;
        *(ushort4*)(dst + i + 4) = u2;
    }
}

// all 4 weight matrices in one launch (region boundaries are multiples of 8)
__global__ __launch_bounds__(256) void convert_wbf_all(
    const float* __restrict__ s0, const float* __restrict__ s1,
    const float* __restrict__ s2, const float* __restrict__ s3)
{
    long long i = ((long long)blockIdx.x * 256 + threadIdx.x) * 8;
    if (i >= WTOT) return;
    const float* src; long long off;
    if (i < WOFF_MEMK)      { src = s0; off = i; }
    else if (i < WOFF_MEMV) { src = s1; off = i - WOFF_MEMK; }
    else if (i < WOFF_PROJ) { src = s2; off = i - WOFF_MEMV; }
    else                    { src = s3; off = i - WOFF_PROJ; }
    float4 a = *(const float4*)(src + off);
    float4 b = *(const float4*)(src + off + 4);
    ushort4 u1; u1.x = f2bf(a.x); u1.y = f2bf(a.y); u1.z = f2bf(a.z); u1.w = f2bf(a.w);
    ushort4 u2; u2.x = f2bf(b.x); u2.y = f2bf(b.y); u2.z = f2bf(b.z); u2.w = f2bf(b.w);
    *(ushort4*)(g_wbf + i)     = u1;
    *(ushort4*)(g_wbf + i + 4) = u2;
}

// ---------------------------------------------------------------------------
// memT[bh][dout][din] = bf16(mem[bh][din][dout])
// ---------------------------------------------------------------------------
__global__ __launch_bounds__(256) void memT_kernel(
    const float* __restrict__ memin, u16* __restrict__ memT)
{
    __shared__ float ml[64 * 65];
    int bh = blockIdx.x, t = threadIdx.x;
    const float* src = memin + (long long)bh * 4096;
#pragma unroll
    for (int i = 0; i < 16; i++) {
        int idx = i * 256 + t;
        ml[(idx >> 6) * 65 + (idx & 63)] = src[idx];
    }
    __syncthreads();
    u16* dst = memT + (long long)bh * 4096;
#pragma unroll
    for (int i = 0; i < 16; i++) {
        int o = i * 256 + t;
        int dout = o >> 6, din = o & 63;
        dst[o] = f2bf(ml[din * 65 + dout]);
    }
}

// ---------------------------------------------------------------------------
// MFMA GEMM v3: as v2 but with the CORRECT involutive slot swizzle.
// phys slot p of row r holds logical k-chunk  p ^ ((r>>1)&3):
//   staging source col = ((t&3) ^ ((t>>3)&3))*8
//   frag read slot     = (kg ^ ((lr>>1)&3))*8
// -> quarter-wave bank classes (lr&1, (lr>>1)&3) = lr&7: 8 classes x 2 lanes
//    = 2-way (free), vs 4/8-way before.
// ---------------------------------------------------------------------------
template<int CF32>
__global__ __launch_bounds__(256) void gemm_mfma(
    const u16* __restrict__ A, long long off0, int rows_per_b,
    long long stride_b, long long stride_r,
    long long w_off, const float* __restrict__ bias,
    void* __restrict__ Cv, int Nout, int nbx)
{
    __shared__ __align__(16) u16 lds[2][2][4096];

    const u16* W = g_wbf + w_off;
    int t = threadIdx.x;

    int wg = blockIdx.x;
    wg = (wg & 7) * ((int)gridDim.x >> 3) + (wg >> 3);
    int m0 = (wg / nbx) * 128;
    int n0 = (wg % nbx) * 128;

    int lane = t & 63, w = t >> 6;
    int w512 = w * 512;

    int srow  = t >> 2;
    int scol  = (((t & 3) ^ ((t >> 3) & 3))) * 8;   // <- bit-corrected swizzle
    long long aoff0, aoff1;
    {
        int g1 = m0 + srow, g2 = g1 + 64;
        int b1 = g1 / rows_per_b, j1 = g1 - b1 * rows_per_b;
        int b2 = g2 / rows_per_b, j2 = g2 - b2 * rows_per_b;
        aoff0 = off0 + (long long)b1 * stride_b + (long long)j1 * stride_r + scol;
        aoff1 = off0 + (long long)b2 * stride_b + (long long)j2 * stride_r + scol;
    }
    const u16* wp0 = W + (long long)(n0 + srow) * 768 + scol;
    const u16* wp1 = W + (long long)(n0 + srow + 64) * 768 + scol;

    int lr = lane & 15, kg = lane >> 4;
    int wm = w >> 1, wn = w & 1;
    int aslot = (kg ^ ((lr >> 1) & 3)) * 8;          // <- matching read swizzle
    int abase = (wm * 64 + lr) * 32 + aslot;
    int bbase = (wn * 64 + lr) * 32 + aslot;

    vf4 acc[4][4];
#pragma unroll
    for (int i = 0; i < 4; i++)
#pragma unroll
        for (int j = 0; j < 4; j++) acc[i][j] = vf4{0.f, 0.f, 0.f, 0.f};

    auto stage = [&](int buf, int kt) {
        gload_lds16(A + aoff0 + kt, &lds[buf][0][w512]);
        gload_lds16(A + aoff1 + kt, &lds[buf][0][2048 + w512]);
        gload_lds16(wp0 + kt,       &lds[buf][1][w512]);
        gload_lds16(wp1 + kt,       &lds[buf][1][2048 + w512]);
    };

    stage(0, 0);
    __syncthreads();

    int cur = 0;
    for (int kt = 0; kt < 768; kt += 32) {
        if (kt != 736) stage(cur ^ 1, kt + 32);

        vbf8 af[4], bf[4];
#pragma unroll
        for (int f = 0; f < 4; f++) {
            af[f] = *(const vbf8*)&lds[cur][0][abase + f * 512];
            bf[f] = *(const vbf8*)&lds[cur][1][bbase + f * 512];
        }
#pragma unroll
        for (int i = 0; i < 4; i++)
#pragma unroll
            for (int j = 0; j < 4; j++)
                acc[i][j] = __builtin_amdgcn_mfma_f32_16x16x32_bf16(
                    af[i], bf[j], acc[i][j], 0, 0, 0);

        __syncthreads();
        cur ^= 1;
    }

    if (!CF32) {
        u16* ct = &lds[0][0][0];
#pragma unroll
        for (int i = 0; i < 4; i++)
#pragma unroll
            for (int j = 0; j < 4; j++) {
                int col = wn * 64 + j * 16 + lr;
                float bb = bias[n0 + col];
#pragma unroll
                for (int r = 0; r < 4; r++)
                    ct[(wm * 64 + i * 16 + kg * 4 + r) * 128 + col] =
                        f2bf(acc[i][j][r] + bb);
            }
        __syncthreads();
        int col0 = (t & 15) * 8;
#pragma unroll
        for (int rr = 0; rr < 8; rr++) {
            int row_l = rr * 16 + (t >> 4);
            vbf8 v = *(const vbf8*)&ct[row_l * 128 + col0];
            *(vbf8*)((u16*)Cv + (long long)(m0 + row_l) * Nout + n0 + col0) = v;
        }
    } else {
        float* cf = (float*)&lds[0][0][0];
#pragma unroll
        for (int p = 0; p < 2; p++) {
            if (wm == p) {
#pragma unroll
                for (int i = 0; i < 4; i++)
#pragma unroll
                    for (int j = 0; j < 4; j++) {
                        int col = wn * 64 + j * 16 + lr;
                        float bb = bias[n0 + col];
#pragma unroll
                        for (int r = 0; r < 4; r++)
                            cf[(i * 16 + kg * 4 + r) * 128 + col] =
                                acc[i][j][r] + bb;
                    }
            }
            __syncthreads();
            int col0 = (t & 15) * 8;
#pragma unroll
            for (int rr = 0; rr < 4; rr++) {
                int row_l = rr * 16 + (t >> 4);
                float4 v0 = *(const float4*)&cf[row_l * 128 + col0];
                float4 v1 = *(const float4*)&cf[row_l * 128 + col0 + 4];
                float* dst = (float*)Cv + (long long)(m0 + p * 64 + row_l) * Nout + n0 + col0;
                *(float4*)dst = v0;
                *(float4*)(dst + 4) = v1;
            }
            __syncthreads();
        }
    }
}

// ---------------------------------------------------------------------------
// attn_s_mfma (unchanged from round 9)
// ---------------------------------------------------------------------------
#define SKP 416
#define VTS 424
__global__ __launch_bounds__(512) void attn_s_mfma(
    const u16* __restrict__ qkv, const u16* __restrict__ memT,
    const float* __restrict__ zin, const float* __restrict__ betas,
    u16* __restrict__ concat)
{
    __shared__ __align__(16) u16 Kl[SKP * 64];
    __shared__ __align__(16) u16 Vt[64 * VTS];
    __shared__ __align__(16) u16 Pl[8][16 * 40];
    __shared__ float red[8][16];

    int bh = blockIdx.x;
    int b = bh / H_, h = bh % H_;
    int t = threadIdx.x, lane = t & 63, w = t >> 6;
    int lr = lane & 15, q4 = lane >> 4;

    {
        int key0 = t >> 3;
        int d0 = (t & 7) * 8;
        for (int kp = 0; kp < SKP; kp += 64) {
            int key = kp + key0;
            if (key < SKP) {
                vbf8 kv, vv;
#pragma unroll
                for (int u = 0; u < 8; u++) { ((short*)&kv)[u] = 0; ((short*)&vv)[u] = 0; }
                if (key < N_) {
                    const u16* base = qkv + ((long long)(b * N_ + key)) * K3 + h * D_;
                    kv = *(const vbf8*)(base + C_ + d0);
                    vv = *(const vbf8*)(base + 2 * C_ + d0);
                }
                *(vbf8*)((char*)Kl + ((key * 128 + d0 * 2) ^ ((key & 7) << 4))) = kv;
#pragma unroll
                for (int u = 0; u < 8; u++) Vt[(d0 + u) * VTS + key] = ((u16*)&vv)[u];
            }
        }
    }
    __syncthreads();

    const float* zp = zin + bh * 64;
    const u16* mtb = memT + (long long)bh * 4096;

    for (int s = w; s < 17; s += 8) {
        int qtok = NT + s * 16 + lr;
        if (qtok > N_ - 1) qtok = N_ - 1;
        const u16* qbase = qkv + ((long long)(b * N_ + qtok)) * K3 + h * D_;
        vbf8 qf0 = *(const vbf8*)(qbase + q4 * 8);
        vbf8 qf1 = *(const vbf8*)(qbase + 32 + q4 * 8);

        vbf8 qs0, qs1;
#pragma unroll
        for (int j = 0; j < 8; j++) {
            ((u16*)&qs0)[j] = f2bf(bf2f(((u16*)&qf0)[j]) * 0.125f);
            ((u16*)&qs1)[j] = f2bf(bf2f(((u16*)&qf1)[j]) * 0.125f);
        }

        vf4 S[13][2];
#pragma unroll
        for (int kt = 0; kt < 13; kt++) {
#pragma unroll
            for (int ks = 0; ks < 2; ks++) {
                int krow = kt * 32 + ks * 16 + lr;
                int swz = (krow & 7) << 4;
                vbf8 b0 = *(const vbf8*)((char*)Kl + ((krow * 128 + q4 * 16) ^ swz));
                vbf8 b1 = *(const vbf8*)((char*)Kl + ((krow * 128 + 64 + q4 * 16) ^ swz));
                vf4 z4 = vf4{0.f, 0.f, 0.f, 0.f};
                vf4 sv = __builtin_amdgcn_mfma_f32_16x16x32_bf16(qs0, b0, z4, 0, 0, 0);
                S[kt][ks] = __builtin_amdgcn_mfma_f32_16x16x32_bf16(qs1, b1, sv, 0, 0, 0);
            }
        }
#pragma unroll
        for (int ks = 0; ks < 2; ks++)
#pragma unroll
            for (int r = 0; r < 4; r++)
                if (ks * 16 + lr >= 4) S[12][ks][r] = -1e30f;

        float mx[4];
#pragma unroll
        for (int r = 0; r < 4; r++) mx[r] = S[0][0][r];
#pragma unroll
        for (int kt = 0; kt < 13; kt++)
#pragma unroll
            for (int ks = 0; ks < 2; ks++)
#pragma unroll
                for (int r = 0; r < 4; r++) mx[r] = fmaxf(mx[r], S[kt][ks][r]);
#pragma unroll
        for (int off = 1; off <= 8; off <<= 1)
#pragma unroll
            for (int r = 0; r < 4; r++) mx[r] = fmaxf(mx[r], __shfl_xor(mx[r], off));

        float l[4] = {0.f, 0.f, 0.f, 0.f};
#pragma unroll
        for (int kt = 0; kt < 13; kt++)
#pragma unroll
            for (int ks = 0; ks < 2; ks++)
#pragma unroll
                for (int r = 0; r < 4; r++) {
                    float p = __expf(S[kt][ks][r] - mx[r]);
                    S[kt][ks][r] = p;
                    l[r] += p;
                }
#pragma unroll
        for (int off = 1; off <= 8; off <<= 1)
#pragma unroll
            for (int r = 0; r < 4; r++) l[r] += __shfl_xor(l[r], off);

        vf4 accO[4];
#pragma unroll
        for (int dc = 0; dc < 4; dc++) accO[dc] = vf4{0.f, 0.f, 0.f, 0.f};
#pragma unroll
        for (int kt = 0; kt < 13; kt++) {
            u16* pw = Pl[w];
#pragma unroll
            for (int ks = 0; ks < 2; ks++)
#pragma unroll
                for (int r = 0; r < 4; r++)
                    pw[(q4 * 4 + r) * 40 + ks * 16 + lr] = f2bf(S[kt][ks][r]);
            vbf8 pf = *(const vbf8*)&Pl[w][lr * 40 + q4 * 8];
#pragma unroll
            for (int dc = 0; dc < 4; dc++) {
                vbf8 vf_ = *(const vbf8*)&Vt[(dc * 16 + lr) * VTS + kt * 32 + q4 * 8];
                accO[dc] = __builtin_amdgcn_mfma_f32_16x16x32_bf16(pf, vf_, accO[dc], 0, 0, 0);
            }
        }

        float invl[4];
#pragma unroll
        for (int r = 0; r < 4; r++) invl[r] = 1.f / l[r];

        vbf8 sq0, sq1;
        float dpart = 0.f;
#pragma unroll
        for (int j = 0; j < 8; j++) {
            float s0 = elu1(bf2f(((u16*)&qf0)[j]));
            float s1 = elu1(bf2f(((u16*)&qf1)[j]));
            ((u16*)&sq0)[j] = f2bf(s0);
            ((u16*)&sq1)[j] = f2bf(s1);
            dpart += s0 * zp[q4 * 8 + j] + s1 * zp[32 + q4 * 8 + j];
        }
        dpart += __shfl_xor(dpart, 16);
        dpart += __shfl_xor(dpart, 32);
        if (q4 == 0) red[w][lr] = dpart;

        vf4 am[4];
#pragma unroll
        for (int dc = 0; dc < 4; dc++) {
            vbf8 b0 = *(const vbf8*)(mtb + (dc * 16 + lr) * 64 + q4 * 8);
            vbf8 b1 = *(const vbf8*)(mtb + (dc * 16 + lr) * 64 + 32 + q4 * 8);
            vf4 z4 = vf4{0.f, 0.f, 0.f, 0.f};
            vf4 a = __builtin_amdgcn_mfma_f32_16x16x32_bf16(sq0, b0, z4, 0, 0, 0);
            am[dc] = __builtin_amdgcn_mfma_f32_16x16x32_bf16(sq1, b1, a, 0, 0, 0);
        }
        float den[4];
#pragma unroll
        for (int r = 0; r < 4; r++) den[r] = 1.f / red[w][q4 * 4 + r];

#pragma unroll
        for (int dc = 0; dc < 4; dc++) {
            float bb = betas[h * D_ + dc * 16 + lr];
            float beta = 1.f / (1.f + __expf(-bb));
#pragma unroll
            for (int r = 0; r < 4; r++) {
                int qs = s * 16 + q4 * 4 + r;
                if (qs < NS) {
                    float o = beta * (am[dc][r] * den[r]) +
                              (1.f - beta) * (accO[dc][r] * invl[r]);
                    concat[((long long)(b * N_ + NT + qs)) * C_ + h * D_ + dc * 16 + lr] = f2bf(o);
                }
            }
        }
    }
}

// ---------------------------------------------------------------------------
// attn_mt_mfma (unchanged from round 9)
// ---------------------------------------------------------------------------
#define MTS 136
__global__ __launch_bounds__(512) void attn_mt_mfma(
    const u16* __restrict__ qkv, u16* __restrict__ concat)
{
    __shared__ __align__(16) u16 Kl[NT * 64];
    __shared__ __align__(16) u16 Vt[64 * MTS];
    __shared__ __align__(16) u16 Pl[8][16 * 40];

    int bh = blockIdx.x;
    int b = bh / H_, h = bh % H_;
    int t = threadIdx.x, lane = t & 63, w = t >> 6;
    int lr = lane & 15, q4 = lane >> 4;

    {
        int key0 = t >> 3;
        int d0 = (t & 7) * 8;
#pragma unroll
        for (int kp = 0; kp < NT; kp += 64) {
            int key = kp + key0;
            const u16* base = qkv + ((long long)(b * N_ + key)) * K3 + h * D_;
            vbf8 kv = *(const vbf8*)(base + C_ + d0);
            vbf8 vv = *(const vbf8*)(base + 2 * C_ + d0);
            *(vbf8*)((char*)Kl + ((key * 128 + d0 * 2) ^ ((key & 7) << 4))) = kv;
#pragma unroll
            for (int u = 0; u < 8; u++) Vt[(d0 + u) * MTS + key] = ((u16*)&vv)[u];
        }
    }
    __syncthreads();

    int qtok = w * 16 + lr;
    const u16* qbase = qkv + ((long long)(b * N_ + qtok)) * K3 + h * D_;
    vbf8 qf0 = *(const vbf8*)(qbase + q4 * 8);
    vbf8 qf1 = *(const vbf8*)(qbase + 32 + q4 * 8);
    vbf8 qs0, qs1;
#pragma unroll
    for (int j = 0; j < 8; j++) {
        ((u16*)&qs0)[j] = f2bf(bf2f(((u16*)&qf0)[j]) * 0.125f);
        ((u16*)&qs1)[j] = f2bf(bf2f(((u16*)&qf1)[j]) * 0.125f);
    }

    vf4 S[4][2];
#pragma unroll
    for (int kt = 0; kt < 4; kt++) {
#pragma unroll
        for (int ks = 0; ks < 2; ks++) {
            int krow = kt * 32 + ks * 16 + lr;
            int swz = (krow & 7) << 4;
            vbf8 b0 = *(const vbf8*)((char*)Kl + ((krow * 128 + q4 * 16) ^ swz));
            vbf8 b1 = *(const vbf8*)((char*)Kl + ((krow * 128 + 64 + q4 * 16) ^ swz));
            vf4 z4 = vf4{0.f, 0.f, 0.f, 0.f};
            vf4 sv = __builtin_amdgcn_mfma_f32_16x16x32_bf16(qs0, b0, z4, 0, 0, 0);
            S[kt][ks] = __builtin_amdgcn_mfma_f32_16x16x32_bf16(qs1, b1, sv, 0, 0, 0);
        }
    }

    float mx[4];
#pragma unroll
    for (int r = 0; r < 4; r++) mx[r] = S[0][0][r];
#pragma unroll
    for (int kt = 0; kt < 4; kt++)
#pragma unroll
        for (int ks = 0; ks < 2; ks++)
#pragma unroll
            for (int r = 0; r < 4; r++) mx[r] = fmaxf(mx[r], S[kt][ks][r]);
#pragma unroll
    for (int off = 1; off <= 8; off <<= 1)
#pragma unroll
        for (int r = 0; r < 4; r++) mx[r] = fmaxf(mx[r], __shfl_xor(mx[r], off));

    float l[4] = {0.f, 0.f, 0.f, 0.f};
#pragma unroll
    for (int kt = 0; kt < 4; kt++)
#pragma unroll
        for (int ks = 0; ks < 2; ks++)
#pragma unroll
            for (int r = 0; r < 4; r++) {
                float p = __expf(S[kt][ks][r] - mx[r]);
                S[kt][ks][r] = p;
                l[r] += p;
            }
#pragma unroll
    for (int off = 1; off <= 8; off <<= 1)
#pragma unroll
        for (int r = 0; r < 4; r++) l[r] += __shfl_xor(l[r], off);

    vf4 accO[4];
#pragma unroll
    for (int dc = 0; dc < 4; dc++) accO[dc] = vf4{0.f, 0.f, 0.f, 0.f};
#pragma unroll
    for (int kt = 0; kt < 4; kt++) {
        u16* pw = Pl[w];
#pragma unroll
        for (int ks = 0; ks < 2; ks++)
#pragma unroll
            for (int r = 0; r < 4; r++)
                pw[(q4 * 4 + r) * 40 + ks * 16 + lr] = f2bf(S[kt][ks][r]);
        vbf8 pf = *(const vbf8*)&Pl[w][lr * 40 + q4 * 8];
#pragma unroll
        for (int dc = 0; dc < 4; dc++) {
            vbf8 vf_ = *(const vbf8*)&Vt[(dc * 16 + lr) * MTS + kt * 32 + q4 * 8];
            accO[dc] = __builtin_amdgcn_mfma_f32_16x16x32_bf16(pf, vf_, accO[dc], 0, 0, 0);
        }
    }

    float invl[4];
#pragma unroll
    for (int r = 0; r < 4; r++) invl[r] = 1.f / l[r];

    int qt0 = w * 16;
#pragma unroll
    for (int dc = 0; dc < 4; dc++)
#pragma unroll
        for (int r = 0; r < 4; r++) {
            int row = qt0 + q4 * 4 + r;
            concat[((long long)(b * N_ + row)) * C_ + h * D_ + dc * 16 + lr] =
                f2bf(accO[dc][r] * invl[r]);
        }
}

// ---------------------------------------------------------------------------
// sigma_pred_mfma (unchanged)
// ---------------------------------------------------------------------------
__global__ __launch_bounds__(512) void sigma_pred_mfma(
    const u16* __restrict__ ksm, const u16* __restrict__ vsm,
    const u16* __restrict__ memT, const float* __restrict__ zin,
    u16* __restrict__ sigT, u16* __restrict__ wT,
    float* __restrict__ z_out)
{
    __shared__ u16 sigLDS[8][64][18];
    __shared__ u16 wLDS[8][64][18];
    __shared__ float red[8][16];
    __shared__ float zpart[8][64];
    __shared__ float zlds[64];

    int bh = blockIdx.x;
    int b = bh / H_, h = bh % H_;
    int t = threadIdx.x, lane = t & 63, w = t >> 6;
    int lr = lane & 15, q4 = lane >> 4;

    if (t < 64) zlds[t] = zin[bh * 64 + t];
    __syncthreads();

    const u16* mtb = memT + (long long)bh * 4096;
    float zacc[16];
#pragma unroll
    for (int j = 0; j < 16; j++) zacc[j] = 0.f;

    for (int s = w; s < 18; s += 8) {
        int n0 = s * 16;
        int nrow = n0 + lr;
        bool vrow = nrow < NS;
        int nclamp = vrow ? nrow : NS - 1;
        const u16* kbase = ksm + ((long long)(b * NS + nclamp)) * C_ + h * D_;
        vbf8 k0 = *(const vbf8*)(kbase + q4 * 8);
        vbf8 k1 = *(const vbf8*)(kbase + 32 + q4 * 8);

        vbf8 sq0, sq1;
        float dpart = 0.f;
#pragma unroll
        for (int j = 0; j < 8; j++) {
            float s0 = vrow ? elu1(bf2f(((u16*)&k0)[j])) : 0.f;
            float s1 = vrow ? elu1(bf2f(((u16*)&k1)[j])) : 0.f;
            ((u16*)&sq0)[j] = f2bf(s0);
            ((u16*)&sq1)[j] = f2bf(s1);
            zacc[j]     += s0;
            zacc[8 + j] += s1;
            dpart += s0 * zlds[q4 * 8 + j] + s1 * zlds[32 + q4 * 8 + j];
        }
        dpart += __shfl_xor(dpart, 16);
        dpart += __shfl_xor(dpart, 32);
        if (q4 == 0) red[w][lr] = dpart;

#pragma unroll
        for (int j = 0; j < 8; j++) {
            sigLDS[w][q4 * 8 + j][lr]      = ((u16*)&sq0)[j];
            sigLDS[w][32 + q4 * 8 + j][lr] = ((u16*)&sq1)[j];
        }

        vf4 am[4];
#pragma unroll
        for (int dc = 0; dc < 4; dc++) {
            vbf8 b0 = *(const vbf8*)(mtb + (dc * 16 + lr) * 64 + q4 * 8);
            vbf8 b1 = *(const vbf8*)(mtb + (dc * 16 + lr) * 64 + 32 + q4 * 8);
            vf4 z4 = vf4{0.f, 0.f, 0.f, 0.f};
            vf4 a = __builtin_amdgcn_mfma_f32_16x16x32_bf16(sq0, b0, z4, 0, 0, 0);
            am[dc] = __builtin_amdgcn_mfma_f32_16x16x32_bf16(sq1, b1, a, 0, 0, 0);
        }
        float rden[4];
#pragma unroll
        for (int r = 0; r < 4; r++) rden[r] = 1.f / red[w][q4 * 4 + r];

#pragma unroll
        for (int dc = 0; dc < 4; dc++) {
            int e = dc * 16 + lr;
#pragma unroll
            for (int r = 0; r < 4; r++) {
                int nn = n0 + q4 * 4 + r;
                float wv = 0.f;
                if (nn < NS) {
                    float pv = am[dc][r] * rden[r];
                    wv = bf2f(vsm[((long long)(b * NS + nn)) * C_ + h * D_ + e]) - pv;
                }
                wLDS[w][e][q4 * 4 + r] = f2bf(wv);
            }
        }

        {
            long long dst = ((long long)bh * 64 + lane) * SPS + n0;
            unsigned pk[8];
#pragma unroll
            for (int j2 = 0; j2 < 8; j2++)
                pk[j2] = (unsigned)sigLDS[w][lane][2 * j2] |
                         ((unsigned)sigLDS[w][lane][2 * j2 + 1] << 16);
            *(uint4*)(sigT + dst)     = uint4{pk[0], pk[1], pk[2], pk[3]};
            *(uint4*)(sigT + dst + 8) = uint4{pk[4], pk[5], pk[6], pk[7]};
#pragma unroll
            for (int j2 = 0; j2 < 8; j2++)
                pk[j2] = (unsigned)wLDS[w][lane][2 * j2] |
                         ((unsigned)wLDS[w][lane][2 * j2 + 1] << 16);
            *(uint4*)(wT + dst)     = uint4{pk[0], pk[1], pk[2], pk[3]};
            *(uint4*)(wT + dst + 8) = uint4{pk[4], pk[5], pk[6], pk[7]};
        }
    }

#pragma unroll
    for (int off = 1; off <= 8; off <<= 1)
#pragma unroll
        for (int j = 0; j < 16; j++) zacc[j] += __shfl_xor(zacc[j], off);
    if (lr == 0) {
#pragma unroll
        for (int j = 0; j < 8; j++) {
            zpart[w][q4 * 8 + j]      = zacc[j];
            zpart[w][32 + q4 * 8 + j] = zacc[8 + j];
        }
    }
    __syncthreads();
    if (t < 64) {
        float tot = 0.f;
#pragma unroll
        for (int ww = 0; ww < 8; ww++) tot += zpart[ww][t];
        z_out[bh * 64 + t] = zlds[t] + tot;
    }
}

// ---------------------------------------------------------------------------
// mem_update_mfma (unchanged)
// ---------------------------------------------------------------------------
__global__ __launch_bounds__(64) void mem_update_mfma(
    const u16* __restrict__ sigT, const u16* __restrict__ wT,
    const float* __restrict__ memin, float* __restrict__ mem_out)
{
    int bh = blockIdx.x;
    int lane = threadIdx.x;
    int lr = lane & 15, q4 = lane >> 4;

    const u16* sb = sigT + (long long)bh * 64 * SPS;
    const u16* wb = wT   + (long long)bh * 64 * SPS;

    vf4 acc[4][4];
#pragma unroll
    for (int i = 0; i < 4; i++)
#pragma unroll
        for (int j = 0; j < 4; j++) acc[i][j] = vf4{0.f, 0.f, 0.f, 0.f};

    for (int kt = 0; kt < SPS; kt += 32) {
        vbf8 af[4], bf[4];
#pragma unroll
        for (int i = 0; i < 4; i++)
            af[i] = *(const vbf8*)(sb + (long long)(i * 16 + lr) * SPS + kt + q4 * 8);
#pragma unroll
        for (int j = 0; j < 4; j++)
            bf[j] = *(const vbf8*)(wb + (long long)(j * 16 + lr) * SPS + kt + q4 * 8);
#pragma unroll
        for (int i = 0; i < 4; i++)
#pragma unroll
            for (int j = 0; j < 4; j++)
                acc[i][j] = __builtin_amdgcn_mfma_f32_16x16x32_bf16(
                    af[i], bf[j], acc[i][j], 0, 0, 0);
    }

    long long mb = (long long)bh * 4096;
#pragma unroll
    for (int i = 0; i < 4; i++)
#pragma unroll
        for (int j = 0; j < 4; j++)
#pragma unroll
            for (int r = 0; r < 4; r++) {
                int d = i * 16 + q4 * 4 + r;
                int e = j * 16 + lr;
                mem_out[mb + d * 64 + e] = memin[mb + d * 64 + e] + acc[i][j][r];
            }
}

// ---------------------------------------------------------------------------
extern "C" void kernel_launch(void* const* d_in, const int* in_sizes, int n_in,
                              void* d_out, int out_size, void* d_ws, size_t ws_size,
                              hipStream_t stream)
{
    const float* x      = (const float*)d_in[0];
    const float* mem    = (const float*)d_in[1];
    const float* z      = (const float*)d_in[2];
    const float* qkv_w  = (const float*)d_in[3];
    const float* qkv_b  = (const float*)d_in[4];
    const float* proj_w = (const float*)d_in[5];
    const float* proj_b = (const float*)d_in[6];
    const float* memk_w = (const float*)d_in[7];
    const float* memk_b = (const float*)d_in[8];
    const float* memv_w = (const float*)d_in[9];
    const float* memv_b = (const float*)d_in[10];
    const float* betas  = (const float*)d_in[11];

    u16* ws     = (u16*)d_ws;
    u16* qkv    = ws;
    u16* ksm    = qkv + QKV_LEN;
    u16* vsm    = ksm + KSM_LEN;
    u16* concat = vsm + KSM_LEN;      // doubles as x_bf before attn writes it

    float* out     = (float*)d_out;
    float* mem_out = out + CAT_LEN;
    float* z_out   = mem_out + MEM_LEN;

    u16* x_bf = concat;               // alias: dead after qkv GEMM
    u16* memT = (u16*)mem_out;        // scratch in mem_out region (overwritten last)
    u16* sigT = qkv;                  // alias: qkv dead after attn kernels
    u16* wT   = qkv + SWT_LEN;

    // 0. conversions
    convert_bf16<<<dim3(2048), dim3(256), 0, stream>>>(x, x_bf, CAT_LEN);
    convert_wbf_all<<<dim3(1728), dim3(256), 0, stream>>>(qkv_w, memk_w, memv_w, proj_w);
    memT_kernel<<<dim3(B_ * H_), dim3(256), 0, stream>>>(mem, memT);

    // 1. qkv = x @ qkv_w^T + qkv_b   (grid 18 x 388 = 6984, %8 == 0)
    gemm_mfma<0><<<dim3(6984), dim3(256), 0, stream>>>(
        x_bf, 0ll, 49664, 0ll, 768ll, WOFF_QKV, qkv_b, qkv, K3, 18);
    // 2. k_s_mem                      (grid 6 x 260 = 1560)
    gemm_mfma<0><<<dim3(1560), dim3(256), 0, stream>>>(
        qkv, (long long)(NT * K3 + C_), NS, (long long)N_ * K3, (long long)K3,
        WOFF_MEMK, memk_b, ksm, C_, 6);
    // 3. v_s_mem
    gemm_mfma<0><<<dim3(1560), dim3(256), 0, stream>>>(
        qkv, (long long)(NT * K3 + 2 * C_), NS, (long long)N_ * K3, (long long)K3,
        WOFF_MEMV, memv_b, vsm, C_, 6);
    // 4. spatial attention (+ mem readout + blend) -> concat[:, NT:]
    attn_s_mfma<<<dim3(B_ * H_), dim3(512), 0, stream>>>(
        qkv, memT, z, betas, concat);
    // 5. token/token attention -> concat[:, :NT]
    attn_mt_mfma<<<dim3(B_ * H_), dim3(512), 0, stream>>>(qkv, concat);
    // 6. sigma/pred -> sigT/wT (overwrites qkv region) + z_new
    sigma_pred_mfma<<<dim3(B_ * H_), dim3(512), 0, stream>>>(
        ksm, vsm, memT, z, sigT, wT, z_out);
    // 7. mem_new = mem + sigT @ wT^T (overwrites memT scratch)
    mem_update_mfma<<<dim3(B_ * H_), dim3(64), 0, stream>>>(
        sigT, wT, mem, mem_out);
    // 8. out = concat @ proj_w^T + proj_b   (grid 6 x 388 = 2328)
    gemm_mfma<1><<<dim3(2328), dim3(256), 0, stream>>>(
        concat, 0ll, 49664, 0ll, 768ll, WOFF_PROJ, proj_b, out, C_, 6);
}

// Round 11
// 887.329 us; speedup vs baseline: 1.1500x; 1.1500x over previous
//
#include <hip/hip_runtime.h>

typedef unsigned short u16;
typedef __attribute__((ext_vector_type(8))) short  vbf8;   // 8 bf16 (4 VGPRs)
typedef __attribute__((ext_vector_type(4))) float  vf4;    // 4 f32 acc

#define B_   128
#define N_   388
#define NT   128
#define NS   260
#define C_   768
#define H_   12
#define D_   64
#define K3   2304   // 3*C

#define QKV_LEN  114425856ll   // 49664*2304  (bf16 ws)
#define KSM_LEN  25559040ll    // 33280*768
#define CAT_LEN  38141952ll    // 49664*768
#define MEM_LEN  6291456ll     // 128*12*64*64 (f32, in d_out)

#define SPS  288               // sigma/w K-extent (keys padded 260->288)
#define SPL  296               // LDS row stride (296/8=37 odd -> even bank spread)

// bf16 weights: [qkv_w | memk_w | memv_w | proj_w]
#define WOFF_QKV  0ll
#define WOFF_MEMK 1769472ll
#define WOFF_MEMV 2359296ll
#define WOFF_PROJ 2949120ll
#define WTOT     3538944ll
__device__ __align__(16) u16 g_wbf[3538944];

__device__ __forceinline__ float bf2f(u16 u) {
    union { unsigned int i; float f; } v; v.i = ((unsigned int)u) << 16; return v.f;
}
__device__ __forceinline__ u16 f2bf(float f) {
    union { float f; unsigned int i; } v; v.f = f;
    unsigned int r = v.i + 0x7fffu + ((v.i >> 16) & 1u);
    return (u16)(r >> 16);
}
__device__ __forceinline__ float elu1(float x) { return x > 0.f ? x + 1.f : __expf(x); }

__device__ __forceinline__ void gload_lds16(const u16* g, u16* l) {
    __builtin_amdgcn_global_load_lds(
        (const __attribute__((address_space(1))) unsigned int*)g,
        (__attribute__((address_space(3))) unsigned int*)l, 16, 0, 0);
}

// ---------------------------------------------------------------------------
// f32 -> bf16 converters
// ---------------------------------------------------------------------------
__global__ __launch_bounds__(256) void convert_bf16(
    const float* __restrict__ src, u16* __restrict__ dst, long long n)
{
    long long i0 = ((long long)blockIdx.x * 256 + threadIdx.x) * 8;
    long long stride = (long long)gridDim.x * 256 * 8;
    for (long long i = i0; i < n; i += stride) {
        float4 a = *(const float4*)(src + i);
        float4 b = *(const float4*)(src + i + 4);
        ushort4 u1; u1.x = f2bf(a.x); u1.y = f2bf(a.y); u1.z = f2bf(a.z); u1.w = f2bf(a.w);
        ushort4 u2; u2.x = f2bf(b.x); u2.y = f2bf(b.y); u2.z = f2bf(b.z); u2.w = f2bf(b.w);
        *(ushort4*)(dst + i)     = u1;
        *(ushort4*)(dst + i + 4) = u2;
    }
}

__global__ __launch_bounds__(256) void convert_wbf_all(
    const float* __restrict__ s0, const float* __restrict__ s1,
    const float* __restrict__ s2, const float* __restrict__ s3)
{
    long long i = ((long long)blockIdx.x * 256 + threadIdx.x) * 8;
    if (i >= WTOT) return;
    const float* src; long long off;
    if (i < WOFF_MEMK)      { src = s0; off = i; }
    else if (i < WOFF_MEMV) { src = s1; off = i - WOFF_MEMK; }
    else if (i < WOFF_PROJ) { src = s2; off = i - WOFF_MEMV; }
    else                    { src = s3; off = i - WOFF_PROJ; }
    float4 a = *(const float4*)(src + off);
    float4 b = *(const float4*)(src + off + 4);
    ushort4 u1; u1.x = f2bf(a.x); u1.y = f2bf(a.y); u1.z = f2bf(a.z); u1.w = f2bf(a.w);
    ushort4 u2; u2.x = f2bf(b.x); u2.y = f2bf(b.y); u2.z = f2bf(b.z); u2.w = f2bf(b.w);
    *(ushort4*)(g_wbf + i)     = u1;
    *(ushort4*)(g_wbf + i + 4) = u2;
}

// ---------------------------------------------------------------------------
// memT[bh][dout][din] = bf16(mem[bh][din][dout])
// ---------------------------------------------------------------------------
__global__ __launch_bounds__(256) void memT_kernel(
    const float* __restrict__ memin, u16* __restrict__ memT)
{
    __shared__ float ml[64 * 65];
    int bh = blockIdx.x, t = threadIdx.x;
    const float* src = memin + (long long)bh * 4096;
#pragma unroll
    for (int i = 0; i < 16; i++) {
        int idx = i * 256 + t;
        ml[(idx >> 6) * 65 + (idx & 63)] = src[idx];
    }
    __syncthreads();
    u16* dst = memT + (long long)bh * 4096;
#pragma unroll
    for (int i = 0; i < 16; i++) {
        int o = i * 256 + t;
        int dout = o >> 6, din = o & 63;
        dst[o] = f2bf(ml[din * 65 + dout]);
    }
}

// ---------------------------------------------------------------------------
// MFMA GEMM (round-9 empirical best: v2 slot swizzle restored)
// ---------------------------------------------------------------------------
template<int CF32>
__global__ __launch_bounds__(256) void gemm_mfma(
    const u16* __restrict__ A, long long off0, int rows_per_b,
    long long stride_b, long long stride_r,
    long long w_off, const float* __restrict__ bias,
    void* __restrict__ Cv, int Nout, int nbx)
{
    __shared__ __align__(16) u16 lds[2][2][4096];

    const u16* W = g_wbf + w_off;
    int t = threadIdx.x;

    int wg = blockIdx.x;
    wg = (wg & 7) * ((int)gridDim.x >> 3) + (wg >> 3);
    int m0 = (wg / nbx) * 128;
    int n0 = (wg % nbx) * 128;

    int lane = t & 63, w = t >> 6;
    int w512 = w * 512;

    int srow  = t >> 2;
    int scol  = (((t & 3) ^ (srow & 3))) * 8;       // v2 swizzle (empirical best)
    long long aoff0, aoff1;
    {
        int g1 = m0 + srow, g2 = g1 + 64;
        int b1 = g1 / rows_per_b, j1 = g1 - b1 * rows_per_b;
        int b2 = g2 / rows_per_b, j2 = g2 - b2 * rows_per_b;
        aoff0 = off0 + (long long)b1 * stride_b + (long long)j1 * stride_r + scol;
        aoff1 = off0 + (long long)b2 * stride_b + (long long)j2 * stride_r + scol;
    }
    const u16* wp0 = W + (long long)(n0 + srow) * 768 + scol;
    const u16* wp1 = W + (long long)(n0 + srow + 64) * 768 + scol;

    int lr = lane & 15, kg = lane >> 4;
    int wm = w >> 1, wn = w & 1;
    int aslot = (kg ^ (lr & 3)) * 8;                 // v2 read swizzle
    int abase = (wm * 64 + lr) * 32 + aslot;
    int bbase = (wn * 64 + lr) * 32 + aslot;

    vf4 acc[4][4];
#pragma unroll
    for (int i = 0; i < 4; i++)
#pragma unroll
        for (int j = 0; j < 4; j++) acc[i][j] = vf4{0.f, 0.f, 0.f, 0.f};

    auto stage = [&](int buf, int kt) {
        gload_lds16(A + aoff0 + kt, &lds[buf][0][w512]);
        gload_lds16(A + aoff1 + kt, &lds[buf][0][2048 + w512]);
        gload_lds16(wp0 + kt,       &lds[buf][1][w512]);
        gload_lds16(wp1 + kt,       &lds[buf][1][2048 + w512]);
    };

    stage(0, 0);
    __syncthreads();

    int cur = 0;
    for (int kt = 0; kt < 768; kt += 32) {
        if (kt != 736) stage(cur ^ 1, kt + 32);

        vbf8 af[4], bf[4];
#pragma unroll
        for (int f = 0; f < 4; f++) {
            af[f] = *(const vbf8*)&lds[cur][0][abase + f * 512];
            bf[f] = *(const vbf8*)&lds[cur][1][bbase + f * 512];
        }
#pragma unroll
        for (int i = 0; i < 4; i++)
#pragma unroll
            for (int j = 0; j < 4; j++)
                acc[i][j] = __builtin_amdgcn_mfma_f32_16x16x32_bf16(
                    af[i], bf[j], acc[i][j], 0, 0, 0);

        __syncthreads();
        cur ^= 1;
    }

    if (!CF32) {
        u16* ct = &lds[0][0][0];
#pragma unroll
        for (int i = 0; i < 4; i++)
#pragma unroll
            for (int j = 0; j < 4; j++) {
                int col = wn * 64 + j * 16 + lr;
                float bb = bias[n0 + col];
#pragma unroll
                for (int r = 0; r < 4; r++)
                    ct[(wm * 64 + i * 16 + kg * 4 + r) * 128 + col] =
                        f2bf(acc[i][j][r] + bb);
            }
        __syncthreads();
        int col0 = (t & 15) * 8;
#pragma unroll
        for (int rr = 0; rr < 8; rr++) {
            int row_l = rr * 16 + (t >> 4);
            vbf8 v = *(const vbf8*)&ct[row_l * 128 + col0];
            *(vbf8*)((u16*)Cv + (long long)(m0 + row_l) * Nout + n0 + col0) = v;
        }
    } else {
        float* cf = (float*)&lds[0][0][0];
#pragma unroll
        for (int p = 0; p < 2; p++) {
            if (wm == p) {
#pragma unroll
                for (int i = 0; i < 4; i++)
#pragma unroll
                    for (int j = 0; j < 4; j++) {
                        int col = wn * 64 + j * 16 + lr;
                        float bb = bias[n0 + col];
#pragma unroll
                        for (int r = 0; r < 4; r++)
                            cf[(i * 16 + kg * 4 + r) * 128 + col] =
                                acc[i][j][r] + bb;
                    }
            }
            __syncthreads();
            int col0 = (t & 15) * 8;
#pragma unroll
            for (int rr = 0; rr < 4; rr++) {
                int row_l = rr * 16 + (t >> 4);
                float4 v0 = *(const float4*)&cf[row_l * 128 + col0];
                float4 v1 = *(const float4*)&cf[row_l * 128 + col0 + 4];
                float* dst = (float*)Cv + (long long)(m0 + p * 64 + row_l) * Nout + n0 + col0;
                *(float4*)dst = v0;
                *(float4*)(dst + 4) = v1;
            }
            __syncthreads();
        }
    }
}

// ---------------------------------------------------------------------------
// attn_s_mfma (unchanged from round 9/10)
// ---------------------------------------------------------------------------
#define SKP 416
#define VTS 424
__global__ __launch_bounds__(512) void attn_s_mfma(
    const u16* __restrict__ qkv, const u16* __restrict__ memT,
    const float* __restrict__ zin, const float* __restrict__ betas,
    u16* __restrict__ concat)
{
    __shared__ __align__(16) u16 Kl[SKP * 64];
    __shared__ __align__(16) u16 Vt[64 * VTS];
    __shared__ __align__(16) u16 Pl[8][16 * 40];
    __shared__ float red[8][16];

    int bh = blockIdx.x;
    int b = bh / H_, h = bh % H_;
    int t = threadIdx.x, lane = t & 63, w = t >> 6;
    int lr = lane & 15, q4 = lane >> 4;

    {
        int key0 = t >> 3;
        int d0 = (t & 7) * 8;
        for (int kp = 0; kp < SKP; kp += 64) {
            int key = kp + key0;
            if (key < SKP) {
                vbf8 kv, vv;
#pragma unroll
                for (int u = 0; u < 8; u++) { ((short*)&kv)[u] = 0; ((short*)&vv)[u] = 0; }
                if (key < N_) {
                    const u16* base = qkv + ((long long)(b * N_ + key)) * K3 + h * D_;
                    kv = *(const vbf8*)(base + C_ + d0);
                    vv = *(const vbf8*)(base + 2 * C_ + d0);
                }
                *(vbf8*)((char*)Kl + ((key * 128 + d0 * 2) ^ ((key & 7) << 4))) = kv;
#pragma unroll
                for (int u = 0; u < 8; u++) Vt[(d0 + u) * VTS + key] = ((u16*)&vv)[u];
            }
        }
    }
    __syncthreads();

    const float* zp = zin + bh * 64;
    const u16* mtb = memT + (long long)bh * 4096;

    for (int s = w; s < 17; s += 8) {
        int qtok = NT + s * 16 + lr;
        if (qtok > N_ - 1) qtok = N_ - 1;
        const u16* qbase = qkv + ((long long)(b * N_ + qtok)) * K3 + h * D_;
        vbf8 qf0 = *(const vbf8*)(qbase + q4 * 8);
        vbf8 qf1 = *(const vbf8*)(qbase + 32 + q4 * 8);

        vbf8 qs0, qs1;
#pragma unroll
        for (int j = 0; j < 8; j++) {
            ((u16*)&qs0)[j] = f2bf(bf2f(((u16*)&qf0)[j]) * 0.125f);
            ((u16*)&qs1)[j] = f2bf(bf2f(((u16*)&qf1)[j]) * 0.125f);
        }

        vf4 S[13][2];
#pragma unroll
        for (int kt = 0; kt < 13; kt++) {
#pragma unroll
            for (int ks = 0; ks < 2; ks++) {
                int krow = kt * 32 + ks * 16 + lr;
                int swz = (krow & 7) << 4;
                vbf8 b0 = *(const vbf8*)((char*)Kl + ((krow * 128 + q4 * 16) ^ swz));
                vbf8 b1 = *(const vbf8*)((char*)Kl + ((krow * 128 + 64 + q4 * 16) ^ swz));
                vf4 z4 = vf4{0.f, 0.f, 0.f, 0.f};
                vf4 sv = __builtin_amdgcn_mfma_f32_16x16x32_bf16(qs0, b0, z4, 0, 0, 0);
                S[kt][ks] = __builtin_amdgcn_mfma_f32_16x16x32_bf16(qs1, b1, sv, 0, 0, 0);
            }
        }
#pragma unroll
        for (int ks = 0; ks < 2; ks++)
#pragma unroll
            for (int r = 0; r < 4; r++)
                if (ks * 16 + lr >= 4) S[12][ks][r] = -1e30f;

        float mx[4];
#pragma unroll
        for (int r = 0; r < 4; r++) mx[r] = S[0][0][r];
#pragma unroll
        for (int kt = 0; kt < 13; kt++)
#pragma unroll
            for (int ks = 0; ks < 2; ks++)
#pragma unroll
                for (int r = 0; r < 4; r++) mx[r] = fmaxf(mx[r], S[kt][ks][r]);
#pragma unroll
        for (int off = 1; off <= 8; off <<= 1)
#pragma unroll
            for (int r = 0; r < 4; r++) mx[r] = fmaxf(mx[r], __shfl_xor(mx[r], off));

        float l[4] = {0.f, 0.f, 0.f, 0.f};
#pragma unroll
        for (int kt = 0; kt < 13; kt++)
#pragma unroll
            for (int ks = 0; ks < 2; ks++)
#pragma unroll
                for (int r = 0; r < 4; r++) {
                    float p = __expf(S[kt][ks][r] - mx[r]);
                    S[kt][ks][r] = p;
                    l[r] += p;
                }
#pragma unroll
        for (int off = 1; off <= 8; off <<= 1)
#pragma unroll
            for (int r = 0; r < 4; r++) l[r] += __shfl_xor(l[r], off);

        vf4 accO[4];
#pragma unroll
        for (int dc = 0; dc < 4; dc++) accO[dc] = vf4{0.f, 0.f, 0.f, 0.f};
#pragma unroll
        for (int kt = 0; kt < 13; kt++) {
            u16* pw = Pl[w];
#pragma unroll
            for (int ks = 0; ks < 2; ks++)
#pragma unroll
                for (int r = 0; r < 4; r++)
                    pw[(q4 * 4 + r) * 40 + ks * 16 + lr] = f2bf(S[kt][ks][r]);
            vbf8 pf = *(const vbf8*)&Pl[w][lr * 40 + q4 * 8];
#pragma unroll
            for (int dc = 0; dc < 4; dc++) {
                vbf8 vf_ = *(const vbf8*)&Vt[(dc * 16 + lr) * VTS + kt * 32 + q4 * 8];
                accO[dc] = __builtin_amdgcn_mfma_f32_16x16x32_bf16(pf, vf_, accO[dc], 0, 0, 0);
            }
        }

        float invl[4];
#pragma unroll
        for (int r = 0; r < 4; r++) invl[r] = 1.f / l[r];

        vbf8 sq0, sq1;
        float dpart = 0.f;
#pragma unroll
        for (int j = 0; j < 8; j++) {
            float s0 = elu1(bf2f(((u16*)&qf0)[j]));
            float s1 = elu1(bf2f(((u16*)&qf1)[j]));
            ((u16*)&sq0)[j] = f2bf(s0);
            ((u16*)&sq1)[j] = f2bf(s1);
            dpart += s0 * zp[q4 * 8 + j] + s1 * zp[32 + q4 * 8 + j];
        }
        dpart += __shfl_xor(dpart, 16);
        dpart += __shfl_xor(dpart, 32);
        if (q4 == 0) red[w][lr] = dpart;

        vf4 am[4];
#pragma unroll
        for (int dc = 0; dc < 4; dc++) {
            vbf8 b0 = *(const vbf8*)(mtb + (dc * 16 + lr) * 64 + q4 * 8);
            vbf8 b1 = *(const vbf8*)(mtb + (dc * 16 + lr) * 64 + 32 + q4 * 8);
            vf4 z4 = vf4{0.f, 0.f, 0.f, 0.f};
            vf4 a = __builtin_amdgcn_mfma_f32_16x16x32_bf16(sq0, b0, z4, 0, 0, 0);
            am[dc] = __builtin_amdgcn_mfma_f32_16x16x32_bf16(sq1, b1, a, 0, 0, 0);
        }
        float den[4];
#pragma unroll
        for (int r = 0; r < 4; r++) den[r] = 1.f / red[w][q4 * 4 + r];

#pragma unroll
        for (int dc = 0; dc < 4; dc++) {
            float bb = betas[h * D_ + dc * 16 + lr];
            float beta = 1.f / (1.f + __expf(-bb));
#pragma unroll
            for (int r = 0; r < 4; r++) {
                int qs = s * 16 + q4 * 4 + r;
                if (qs < NS) {
                    float o = beta * (am[dc][r] * den[r]) +
                              (1.f - beta) * (accO[dc][r] * invl[r]);
                    concat[((long long)(b * N_ + NT + qs)) * C_ + h * D_ + dc * 16 + lr] = f2bf(o);
                }
            }
        }
    }
}

// ---------------------------------------------------------------------------
// attn_mt_mfma (unchanged)
// ---------------------------------------------------------------------------
#define MTS 136
__global__ __launch_bounds__(512) void attn_mt_mfma(
    const u16* __restrict__ qkv, u16* __restrict__ concat)
{
    __shared__ __align__(16) u16 Kl[NT * 64];
    __shared__ __align__(16) u16 Vt[64 * MTS];
    __shared__ __align__(16) u16 Pl[8][16 * 40];

    int bh = blockIdx.x;
    int b = bh / H_, h = bh % H_;
    int t = threadIdx.x, lane = t & 63, w = t >> 6;
    int lr = lane & 15, q4 = lane >> 4;

    {
        int key0 = t >> 3;
        int d0 = (t & 7) * 8;
#pragma unroll
        for (int kp = 0; kp < NT; kp += 64) {
            int key = kp + key0;
            const u16* base = qkv + ((long long)(b * N_ + key)) * K3 + h * D_;
            vbf8 kv = *(const vbf8*)(base + C_ + d0);
            vbf8 vv = *(const vbf8*)(base + 2 * C_ + d0);
            *(vbf8*)((char*)Kl + ((key * 128 + d0 * 2) ^ ((key & 7) << 4))) = kv;
#pragma unroll
            for (int u = 0; u < 8; u++) Vt[(d0 + u) * MTS + key] = ((u16*)&vv)[u];
        }
    }
    __syncthreads();

    int qtok = w * 16 + lr;
    const u16* qbase = qkv + ((long long)(b * N_ + qtok)) * K3 + h * D_;
    vbf8 qf0 = *(const vbf8*)(qbase + q4 * 8);
    vbf8 qf1 = *(const vbf8*)(qbase + 32 + q4 * 8);
    vbf8 qs0, qs1;
#pragma unroll
    for (int j = 0; j < 8; j++) {
        ((u16*)&qs0)[j] = f2bf(bf2f(((u16*)&qf0)[j]) * 0.125f);
        ((u16*)&qs1)[j] = f2bf(bf2f(((u16*)&qf1)[j]) * 0.125f);
    }

    vf4 S[4][2];
#pragma unroll
    for (int kt = 0; kt < 4; kt++) {
#pragma unroll
        for (int ks = 0; ks < 2; ks++) {
            int krow = kt * 32 + ks * 16 + lr;
            int swz = (krow & 7) << 4;
            vbf8 b0 = *(const vbf8*)((char*)Kl + ((krow * 128 + q4 * 16) ^ swz));
            vbf8 b1 = *(const vbf8*)((char*)Kl + ((krow * 128 + 64 + q4 * 16) ^ swz));
            vf4 z4 = vf4{0.f, 0.f, 0.f, 0.f};
            vf4 sv = __builtin_amdgcn_mfma_f32_16x16x32_bf16(qs0, b0, z4, 0, 0, 0);
            S[kt][ks] = __builtin_amdgcn_mfma_f32_16x16x32_bf16(qs1, b1, sv, 0, 0, 0);
        }
    }

    float mx[4];
#pragma unroll
    for (int r = 0; r < 4; r++) mx[r] = S[0][0][r];
#pragma unroll
    for (int kt = 0; kt < 4; kt++)
#pragma unroll
        for (int ks = 0; ks < 2; ks++)
#pragma unroll
            for (int r = 0; r < 4; r++) mx[r] = fmaxf(mx[r], S[kt][ks][r]);
#pragma unroll
    for (int off = 1; off <= 8; off <<= 1)
#pragma unroll
        for (int r = 0; r < 4; r++) mx[r] = fmaxf(mx[r], __shfl_xor(mx[r], off));

    float l[4] = {0.f, 0.f, 0.f, 0.f};
#pragma unroll
    for (int kt = 0; kt < 4; kt++)
#pragma unroll
        for (int ks = 0; ks < 2; ks++)
#pragma unroll
            for (int r = 0; r < 4; r++) {
                float p = __expf(S[kt][ks][r] - mx[r]);
                S[kt][ks][r] = p;
                l[r] += p;
            }
#pragma unroll
    for (int off = 1; off <= 8; off <<= 1)
#pragma unroll
        for (int r = 0; r < 4; r++) l[r] += __shfl_xor(l[r], off);

    vf4 accO[4];
#pragma unroll
    for (int dc = 0; dc < 4; dc++) accO[dc] = vf4{0.f, 0.f, 0.f, 0.f};
#pragma unroll
    for (int kt = 0; kt < 4; kt++) {
        u16* pw = Pl[w];
#pragma unroll
        for (int ks = 0; ks < 2; ks++)
#pragma unroll
            for (int r = 0; r < 4; r++)
                pw[(q4 * 4 + r) * 40 + ks * 16 + lr] = f2bf(S[kt][ks][r]);
        vbf8 pf = *(const vbf8*)&Pl[w][lr * 40 + q4 * 8];
#pragma unroll
        for (int dc = 0; dc < 4; dc++) {
            vbf8 vf_ = *(const vbf8*)&Vt[(dc * 16 + lr) * MTS + kt * 32 + q4 * 8];
            accO[dc] = __builtin_amdgcn_mfma_f32_16x16x32_bf16(pf, vf_, accO[dc], 0, 0, 0);
        }
    }

    float invl[4];
#pragma unroll
    for (int r = 0; r < 4; r++) invl[r] = 1.f / l[r];

    int qt0 = w * 16;
#pragma unroll
    for (int dc = 0; dc < 4; dc++)
#pragma unroll
        for (int r = 0; r < 4; r++) {
            int row = qt0 + q4 * 4 + r;
            concat[((long long)(b * N_ + row)) * C_ + h * D_ + dc * 16 + lr] =
                f2bf(accO[dc][r] * invl[r]);
        }
}

// ---------------------------------------------------------------------------
// sigma_pred_mem: fused sigma/pred + mem_new. Per (b,h), 512 thr (8 waves).
// Phase 1 (per-wave strips, no barrier): sigma = elu(ksm)+1, num = sigma@memT
// (MFMA), den = sigma.z, w = vsm - num/den; write sigma/w TRANSPOSED into
// LDS [d/e][n] (stride SPL=296: 296/8=37 odd -> even bank-group spread).
// Phase 2 (one barrier): 8 waves split the 16 16x16 output tiles of
// mem_new = mem + sigL @ wL^T over K=288. z_new from column sums.
// ---------------------------------------------------------------------------
__global__ __launch_bounds__(512) void sigma_pred_mem(
    const u16* __restrict__ ksm, const u16* __restrict__ vsm,
    const u16* __restrict__ memT, const float* __restrict__ zin,
    const float* __restrict__ memin, float* __restrict__ mem_out,
    float* __restrict__ z_out)
{
    __shared__ __align__(16) u16 sigL[64][SPL];
    __shared__ __align__(16) u16 wL[64][SPL];
    __shared__ float red[8][16];
    __shared__ float zpart[8][64];
    __shared__ float zlds[64];

    int bh = blockIdx.x;
    int b = bh / H_, h = bh % H_;
    int t = threadIdx.x, lane = t & 63, w = t >> 6;
    int lr = lane & 15, q4 = lane >> 4;

    if (t < 64) zlds[t] = zin[bh * 64 + t];
    __syncthreads();

    const u16* mtb = memT + (long long)bh * 4096;
    float zacc[16];
#pragma unroll
    for (int j = 0; j < 16; j++) zacc[j] = 0.f;

    for (int s = w; s < 18; s += 8) {
        int n0 = s * 16;
        int nrow = n0 + lr;
        bool vrow = nrow < NS;
        int nclamp = vrow ? nrow : NS - 1;
        const u16* kbase = ksm + ((long long)(b * NS + nclamp)) * C_ + h * D_;
        vbf8 k0 = *(const vbf8*)(kbase + q4 * 8);
        vbf8 k1 = *(const vbf8*)(kbase + 32 + q4 * 8);

        vbf8 sq0, sq1;
        float dpart = 0.f;
#pragma unroll
        for (int j = 0; j < 8; j++) {
            float s0 = vrow ? elu1(bf2f(((u16*)&k0)[j])) : 0.f;
            float s1 = vrow ? elu1(bf2f(((u16*)&k1)[j])) : 0.f;
            u16 b0 = f2bf(s0), b1 = f2bf(s1);
            ((u16*)&sq0)[j] = b0;
            ((u16*)&sq1)[j] = b1;
            zacc[j]     += s0;
            zacc[8 + j] += s1;
            dpart += s0 * zlds[q4 * 8 + j] + s1 * zlds[32 + q4 * 8 + j];
            sigL[q4 * 8 + j][n0 + lr]      = b0;   // [d][n] transposed store
            sigL[32 + q4 * 8 + j][n0 + lr] = b1;
        }
        dpart += __shfl_xor(dpart, 16);
        dpart += __shfl_xor(dpart, 32);
        if (q4 == 0) red[w][lr] = dpart;

        vf4 am[4];
#pragma unroll
        for (int dc = 0; dc < 4; dc++) {
            vbf8 b0 = *(const vbf8*)(mtb + (dc * 16 + lr) * 64 + q4 * 8);
            vbf8 b1 = *(const vbf8*)(mtb + (dc * 16 + lr) * 64 + 32 + q4 * 8);
            vf4 z4 = vf4{0.f, 0.f, 0.f, 0.f};
            vf4 a = __builtin_amdgcn_mfma_f32_16x16x32_bf16(sq0, b0, z4, 0, 0, 0);
            am[dc] = __builtin_amdgcn_mfma_f32_16x16x32_bf16(sq1, b1, a, 0, 0, 0);
        }
        float rden[4];
#pragma unroll
        for (int r = 0; r < 4; r++) rden[r] = 1.f / red[w][q4 * 4 + r];

#pragma unroll
        for (int dc = 0; dc < 4; dc++) {
            int e = dc * 16 + lr;
#pragma unroll
            for (int r = 0; r < 4; r++) {
                int nn = n0 + q4 * 4 + r;
                float wv = 0.f;
                if (nn < NS) {
                    float pv = am[dc][r] * rden[r];
                    wv = bf2f(vsm[((long long)(b * NS + nn)) * C_ + h * D_ + e]) - pv;
                }
                wL[e][n0 + q4 * 4 + r] = f2bf(wv);   // [e][n] transposed store
            }
        }
    }

    // column sums for z_new
#pragma unroll
    for (int off = 1; off <= 8; off <<= 1)
#pragma unroll
        for (int j = 0; j < 16; j++) zacc[j] += __shfl_xor(zacc[j], off);
    if (lr == 0) {
#pragma unroll
        for (int j = 0; j < 8; j++) {
            zpart[w][q4 * 8 + j]      = zacc[j];
            zpart[w][32 + q4 * 8 + j] = zacc[8 + j];
        }
    }
    __syncthreads();   // sigL/wL complete + zpart ready

    if (t < 64) {
        float tot = 0.f;
#pragma unroll
        for (int ww = 0; ww < 8; ww++) tot += zpart[ww][t];
        z_out[bh * 64 + t] = zlds[t] + tot;
    }

    // mem_new GEMM: wave w -> output tiles 2w, 2w+1 (of 4x4 16x16 tiles)
    long long mb = (long long)bh * 4096;
#pragma unroll
    for (int p = 0; p < 2; p++) {
        int tid2 = w * 2 + p;
        int i = tid2 >> 2, j = tid2 & 3;
        vf4 acc = vf4{0.f, 0.f, 0.f, 0.f};
#pragma unroll
        for (int kt = 0; kt < SPS; kt += 32) {
            vbf8 af = *(const vbf8*)&sigL[i * 16 + lr][kt + q4 * 8];
            vbf8 bf = *(const vbf8*)&wL[j * 16 + lr][kt + q4 * 8];
            acc = __builtin_amdgcn_mfma_f32_16x16x32_bf16(af, bf, acc, 0, 0, 0);
        }
        int e = j * 16 + lr;
#pragma unroll
        for (int r = 0; r < 4; r++) {
            int dd = i * 16 + q4 * 4 + r;
            mem_out[mb + dd * 64 + e] = memin[mb + dd * 64 + e] + acc[r];
        }
    }
}

// ---------------------------------------------------------------------------
extern "C" void kernel_launch(void* const* d_in, const int* in_sizes, int n_in,
                              void* d_out, int out_size, void* d_ws, size_t ws_size,
                              hipStream_t stream)
{
    const float* x      = (const float*)d_in[0];
    const float* mem    = (const float*)d_in[1];
    const float* z      = (const float*)d_in[2];
    const float* qkv_w  = (const float*)d_in[3];
    const float* qkv_b  = (const float*)d_in[4];
    const float* proj_w = (const float*)d_in[5];
    const float* proj_b = (const float*)d_in[6];
    const float* memk_w = (const float*)d_in[7];
    const float* memk_b = (const float*)d_in[8];
    const float* memv_w = (const float*)d_in[9];
    const float* memv_b = (const float*)d_in[10];
    const float* betas  = (const float*)d_in[11];

    u16* ws     = (u16*)d_ws;
    u16* qkv    = ws;
    u16* ksm    = qkv + QKV_LEN;
    u16* vsm    = ksm + KSM_LEN;
    u16* concat = vsm + KSM_LEN;      // doubles as x_bf before attn writes it

    float* out     = (float*)d_out;
    float* mem_out = out + CAT_LEN;
    float* z_out   = mem_out + MEM_LEN;

    u16* x_bf = concat;               // alias: dead after qkv GEMM
    u16* memT = (u16*)out;            // scratch at d_out base; proj overwrites LAST

    // 0. conversions
    convert_bf16<<<dim3(2048), dim3(256), 0, stream>>>(x, x_bf, CAT_LEN);
    convert_wbf_all<<<dim3(1728), dim3(256), 0, stream>>>(qkv_w, memk_w, memv_w, proj_w);
    memT_kernel<<<dim3(B_ * H_), dim3(256), 0, stream>>>(mem, memT);

    // 1. qkv = x @ qkv_w^T + qkv_b   (grid 18 x 388 = 6984, %8 == 0)
    gemm_mfma<0><<<dim3(6984), dim3(256), 0, stream>>>(
        x_bf, 0ll, 49664, 0ll, 768ll, WOFF_QKV, qkv_b, qkv, K3, 18);
    // 2. k_s_mem                      (grid 6 x 260 = 1560)
    gemm_mfma<0><<<dim3(1560), dim3(256), 0, stream>>>(
        qkv, (long long)(NT * K3 + C_), NS, (long long)N_ * K3, (long long)K3,
        WOFF_MEMK, memk_b, ksm, C_, 6);
    // 3. v_s_mem
    gemm_mfma<0><<<dim3(1560), dim3(256), 0, stream>>>(
        qkv, (long long)(NT * K3 + 2 * C_), NS, (long long)N_ * K3, (long long)K3,
        WOFF_MEMV, memv_b, vsm, C_, 6);
    // 4. spatial attention (+ mem readout + blend) -> concat[:, NT:]
    attn_s_mfma<<<dim3(B_ * H_), dim3(512), 0, stream>>>(
        qkv, memT, z, betas, concat);
    // 5. token/token attention -> concat[:, :NT]
    attn_mt_mfma<<<dim3(B_ * H_), dim3(512), 0, stream>>>(qkv, concat);
    // 6+7. fused sigma/pred + z_new + mem_new
    sigma_pred_mem<<<dim3(B_ * H_), dim3(512), 0, stream>>>(
        ksm, vsm, memT, z, mem, mem_out, z_out);
    // 8. out = concat @ proj_w^T + proj_b   (grid 6 x 388 = 2328; overwrites memT)
    gemm_mfma<1><<<dim3(2328), dim3(256), 0, stream>>>(
        concat, 0ll, 49664, 0ll, 768ll, WOFF_PROJ, proj_b, out, C_, 6);
}

// Round 12
// 858.433 us; speedup vs baseline: 1.1887x; 1.0337x over previous
//
#include <hip/hip_runtime.h>

typedef unsigned short u16;
typedef __attribute__((ext_vector_type(8))) short  vbf8;   // 8 bf16 (4 VGPRs)
typedef __attribute__((ext_vector_type(4))) float  vf4;    // 4 f32 acc

#define B_   128
#define N_   388
#define NT   128
#define NS   260
#define C_   768
#define H_   12
#define D_   64
#define K3   2304   // 3*C

#define QKV_LEN  114425856ll   // 49664*2304  (bf16 ws)
#define KSM_LEN  25559040ll    // 33280*768
#define CAT_LEN  38141952ll    // 49664*768
#define MEM_LEN  6291456ll     // 128*12*64*64 (f32, in d_out)

#define SPS  288               // sigma/w K-extent (keys padded 260->288)
#define SPL  296               // LDS row stride

// bf16 weights: [qkv_w | memk_w | memv_w | proj_w]
#define WOFF_QKV  0ll
#define WOFF_MEMK 1769472ll
#define WOFF_MEMV 2359296ll
#define WOFF_PROJ 2949120ll
#define WTOT     3538944ll
__device__ __align__(16) u16 g_wbf[3538944];

__device__ __forceinline__ float bf2f(u16 u) {
    union { unsigned int i; float f; } v; v.i = ((unsigned int)u) << 16; return v.f;
}
__device__ __forceinline__ u16 f2bf(float f) {
    union { float f; unsigned int i; } v; v.f = f;
    unsigned int r = v.i + 0x7fffu + ((v.i >> 16) & 1u);
    return (u16)(r >> 16);
}
__device__ __forceinline__ float elu1(float x) { return x > 0.f ? x + 1.f : __expf(x); }

__device__ __forceinline__ void gload_lds16(const u16* g, u16* l) {
    __builtin_amdgcn_global_load_lds(
        (const __attribute__((address_space(1))) unsigned int*)g,
        (__attribute__((address_space(3))) unsigned int*)l, 16, 0, 0);
}

// ---------------------------------------------------------------------------
// merged converters: blocks [0,2048) -> x (grid-stride); rest -> weights
// ---------------------------------------------------------------------------
__global__ __launch_bounds__(256) void convert_all(
    const float* __restrict__ x, u16* __restrict__ x_bf,
    const float* __restrict__ s0, const float* __restrict__ s1,
    const float* __restrict__ s2, const float* __restrict__ s3)
{
    int bid = blockIdx.x;
    if (bid < 2048) {
        long long i0 = ((long long)bid * 256 + threadIdx.x) * 8;
        long long stride = 2048ll * 256 * 8;
        for (long long i = i0; i < CAT_LEN; i += stride) {
            float4 a = *(const float4*)(x + i);
            float4 b = *(const float4*)(x + i + 4);
            ushort4 u1; u1.x = f2bf(a.x); u1.y = f2bf(a.y); u1.z = f2bf(a.z); u1.w = f2bf(a.w);
            ushort4 u2; u2.x = f2bf(b.x); u2.y = f2bf(b.y); u2.z = f2bf(b.z); u2.w = f2bf(b.w);
            *(ushort4*)(x_bf + i)     = u1;
            *(ushort4*)(x_bf + i + 4) = u2;
        }
    } else {
        long long i = ((long long)(bid - 2048) * 256 + threadIdx.x) * 8;
        if (i >= WTOT) return;
        const float* src; long long off;
        if (i < WOFF_MEMK)      { src = s0; off = i; }
        else if (i < WOFF_MEMV) { src = s1; off = i - WOFF_MEMK; }
        else if (i < WOFF_PROJ) { src = s2; off = i - WOFF_MEMV; }
        else                    { src = s3; off = i - WOFF_PROJ; }
        float4 a = *(const float4*)(src + off);
        float4 b = *(const float4*)(src + off + 4);
        ushort4 u1; u1.x = f2bf(a.x); u1.y = f2bf(a.y); u1.z = f2bf(a.z); u1.w = f2bf(a.w);
        ushort4 u2; u2.x = f2bf(b.x); u2.y = f2bf(b.y); u2.z = f2bf(b.z); u2.w = f2bf(b.w);
        *(ushort4*)(g_wbf + i)     = u1;
        *(ushort4*)(g_wbf + i + 4) = u2;
    }
}

// ---------------------------------------------------------------------------
// memT[bh][dout][din] = bf16(mem[bh][din][dout])
// ---------------------------------------------------------------------------
__global__ __launch_bounds__(256) void memT_kernel(
    const float* __restrict__ memin, u16* __restrict__ memT)
{
    __shared__ float ml[64 * 65];
    int bh = blockIdx.x, t = threadIdx.x;
    const float* src = memin + (long long)bh * 4096;
#pragma unroll
    for (int i = 0; i < 16; i++) {
        int idx = i * 256 + t;
        ml[(idx >> 6) * 65 + (idx & 63)] = src[idx];
    }
    __syncthreads();
    u16* dst = memT + (long long)bh * 4096;
#pragma unroll
    for (int i = 0; i < 16; i++) {
        int o = i * 256 + t;
        int dout = o >> 6, din = o & 63;
        dst[o] = f2bf(ml[din * 65 + dout]);
    }
}

// ---------------------------------------------------------------------------
// MFMA GEMM body (round-9/11 empirical best structure, v2 slot swizzle)
// ---------------------------------------------------------------------------
template<int CF32>
__device__ __forceinline__ void gemm_body(
    int wgid, int ngrid,
    const u16* __restrict__ A, long long off0, int rows_per_b,
    long long stride_b, long long stride_r,
    const u16* __restrict__ W, const float* __restrict__ bias,
    void* __restrict__ Cv, int Nout, int nbx)
{
    __shared__ __align__(16) u16 lds[2][2][4096];

    int t = threadIdx.x;

    int wg = (wgid & 7) * (ngrid >> 3) + (wgid >> 3);
    int m0 = (wg / nbx) * 128;
    int n0 = (wg % nbx) * 128;

    int lane = t & 63, w = t >> 6;
    int w512 = w * 512;

    int srow  = t >> 2;
    int scol  = (((t & 3) ^ (srow & 3))) * 8;
    long long aoff0, aoff1;
    {
        int g1 = m0 + srow, g2 = g1 + 64;
        int b1 = g1 / rows_per_b, j1 = g1 - b1 * rows_per_b;
        int b2 = g2 / rows_per_b, j2 = g2 - b2 * rows_per_b;
        aoff0 = off0 + (long long)b1 * stride_b + (long long)j1 * stride_r + scol;
        aoff1 = off0 + (long long)b2 * stride_b + (long long)j2 * stride_r + scol;
    }
    const u16* wp0 = W + (long long)(n0 + srow) * 768 + scol;
    const u16* wp1 = W + (long long)(n0 + srow + 64) * 768 + scol;

    int lr = lane & 15, kg = lane >> 4;
    int wm = w >> 1, wn = w & 1;
    int aslot = (kg ^ (lr & 3)) * 8;
    int abase = (wm * 64 + lr) * 32 + aslot;
    int bbase = (wn * 64 + lr) * 32 + aslot;

    vf4 acc[4][4];
#pragma unroll
    for (int i = 0; i < 4; i++)
#pragma unroll
        for (int j = 0; j < 4; j++) acc[i][j] = vf4{0.f, 0.f, 0.f, 0.f};

    auto stage = [&](int buf, int kt) {
        gload_lds16(A + aoff0 + kt, &lds[buf][0][w512]);
        gload_lds16(A + aoff1 + kt, &lds[buf][0][2048 + w512]);
        gload_lds16(wp0 + kt,       &lds[buf][1][w512]);
        gload_lds16(wp1 + kt,       &lds[buf][1][2048 + w512]);
    };

    stage(0, 0);
    __syncthreads();

    int cur = 0;
    for (int kt = 0; kt < 768; kt += 32) {
        if (kt != 736) stage(cur ^ 1, kt + 32);

        vbf8 af[4], bf[4];
#pragma unroll
        for (int f = 0; f < 4; f++) {
            af[f] = *(const vbf8*)&lds[cur][0][abase + f * 512];
            bf[f] = *(const vbf8*)&lds[cur][1][bbase + f * 512];
        }
#pragma unroll
        for (int i = 0; i < 4; i++)
#pragma unroll
            for (int j = 0; j < 4; j++)
                acc[i][j] = __builtin_amdgcn_mfma_f32_16x16x32_bf16(
                    af[i], bf[j], acc[i][j], 0, 0, 0);

        __syncthreads();
        cur ^= 1;
    }

    if (!CF32) {
        u16* ct = &lds[0][0][0];
#pragma unroll
        for (int i = 0; i < 4; i++)
#pragma unroll
            for (int j = 0; j < 4; j++) {
                int col = wn * 64 + j * 16 + lr;
                float bb = bias[n0 + col];
#pragma unroll
                for (int r = 0; r < 4; r++)
                    ct[(wm * 64 + i * 16 + kg * 4 + r) * 128 + col] =
                        f2bf(acc[i][j][r] + bb);
            }
        __syncthreads();
        int col0 = (t & 15) * 8;
#pragma unroll
        for (int rr = 0; rr < 8; rr++) {
            int row_l = rr * 16 + (t >> 4);
            vbf8 v = *(const vbf8*)&ct[row_l * 128 + col0];
            *(vbf8*)((u16*)Cv + (long long)(m0 + row_l) * Nout + n0 + col0) = v;
        }
    } else {
        float* cf = (float*)&lds[0][0][0];
#pragma unroll
        for (int p = 0; p < 2; p++) {
            if (wm == p) {
#pragma unroll
                for (int i = 0; i < 4; i++)
#pragma unroll
                    for (int j = 0; j < 4; j++) {
                        int col = wn * 64 + j * 16 + lr;
                        float bb = bias[n0 + col];
#pragma unroll
                        for (int r = 0; r < 4; r++)
                            cf[(i * 16 + kg * 4 + r) * 128 + col] =
                                acc[i][j][r] + bb;
                    }
            }
            __syncthreads();
            int col0 = (t & 15) * 8;
#pragma unroll
            for (int rr = 0; rr < 4; rr++) {
                int row_l = rr * 16 + (t >> 4);
                float4 v0 = *(const float4*)&cf[row_l * 128 + col0];
                float4 v1 = *(const float4*)&cf[row_l * 128 + col0 + 4];
                float* dst = (float*)Cv + (long long)(m0 + p * 64 + row_l) * Nout + n0 + col0;
                *(float4*)dst = v0;
                *(float4*)(dst + 4) = v1;
            }
            __syncthreads();
        }
    }
}

template<int CF32>
__global__ __launch_bounds__(256) void gemm_mfma(
    const u16* __restrict__ A, long long off0, int rows_per_b,
    long long stride_b, long long stride_r,
    long long w_off, const float* __restrict__ bias,
    void* __restrict__ Cv, int Nout, int nbx)
{
    gemm_body<CF32>(blockIdx.x, gridDim.x, A, off0, rows_per_b, stride_b,
                    stride_r, g_wbf + w_off, bias, Cv, Nout, nbx);
}

// dual GEMM: first `half` blocks -> params a (memk), rest -> params b (memv)
__global__ __launch_bounds__(256) void gemm_mfma_dual(
    const u16* __restrict__ A, long long off0a, long long off0b,
    int rows_per_b, long long stride_b, long long stride_r,
    long long w_offa, long long w_offb,
    const float* __restrict__ biasa, const float* __restrict__ biasb,
    void* __restrict__ Cva, void* __restrict__ Cvb, int Nout, int nbx, int half)
{
    int bid = blockIdx.x;
    if (bid < half)
        gemm_body<0>(bid, half, A, off0a, rows_per_b, stride_b, stride_r,
                     g_wbf + w_offa, biasa, Cva, Nout, nbx);
    else
        gemm_body<0>(bid - half, half, A, off0b, rows_per_b, stride_b, stride_r,
                     g_wbf + w_offb, biasb, Cvb, Nout, nbx);
}

// ---------------------------------------------------------------------------
// attn_fused: one block per (b,h), 512 thr (8 waves). Stages all 388 K/V
// once (SKP=416 padded). S-part: 17 strips (full-row softmax + mem readout
// + blend) exactly as round 9. MT-part FUSED IN: 8 strips over q-rows
// 0..127, keys 0..127 (tiles 0..3, already resident) -> concat[:, :NT].
// MT strips are assigned to waves 1..7 (w1 gets 2) so every wave's total
// load stays <= wave 0's existing 3-S-strip critical path.
// ---------------------------------------------------------------------------
#define SKP 416
#define VTS 424
__global__ __launch_bounds__(512) void attn_fused(
    const u16* __restrict__ qkv, const u16* __restrict__ memT,
    const float* __restrict__ zin, const float* __restrict__ betas,
    u16* __restrict__ concat)
{
    __shared__ __align__(16) u16 Kl[SKP * 64];
    __shared__ __align__(16) u16 Vt[64 * VTS];
    __shared__ __align__(16) u16 Pl[8][16 * 40];
    __shared__ float red[8][16];

    int bh = blockIdx.x;
    int b = bh / H_, h = bh % H_;
    int t = threadIdx.x, lane = t & 63, w = t >> 6;
    int lr = lane & 15, q4 = lane >> 4;

    {
        int key0 = t >> 3;
        int d0 = (t & 7) * 8;
        for (int kp = 0; kp < SKP; kp += 64) {
            int key = kp + key0;
            if (key < SKP) {
                vbf8 kv, vv;
#pragma unroll
                for (int u = 0; u < 8; u++) { ((short*)&kv)[u] = 0; ((short*)&vv)[u] = 0; }
                if (key < N_) {
                    const u16* base = qkv + ((long long)(b * N_ + key)) * K3 + h * D_;
                    kv = *(const vbf8*)(base + C_ + d0);
                    vv = *(const vbf8*)(base + 2 * C_ + d0);
                }
                *(vbf8*)((char*)Kl + ((key * 128 + d0 * 2) ^ ((key & 7) << 4))) = kv;
#pragma unroll
                for (int u = 0; u < 8; u++) Vt[(d0 + u) * VTS + key] = ((u16*)&vv)[u];
            }
        }
    }
    __syncthreads();

    const float* zp = zin + bh * 64;
    const u16* mtb = memT + (long long)bh * 4096;

    // ---------------- S-part strips (rows NT..N) ----------------
    for (int s = w; s < 17; s += 8) {
        int qtok = NT + s * 16 + lr;
        if (qtok > N_ - 1) qtok = N_ - 1;
        const u16* qbase = qkv + ((long long)(b * N_ + qtok)) * K3 + h * D_;
        vbf8 qf0 = *(const vbf8*)(qbase + q4 * 8);
        vbf8 qf1 = *(const vbf8*)(qbase + 32 + q4 * 8);

        vbf8 qs0, qs1;
#pragma unroll
        for (int j = 0; j < 8; j++) {
            ((u16*)&qs0)[j] = f2bf(bf2f(((u16*)&qf0)[j]) * 0.125f);
            ((u16*)&qs1)[j] = f2bf(bf2f(((u16*)&qf1)[j]) * 0.125f);
        }

        vf4 S[13][2];
#pragma unroll
        for (int kt = 0; kt < 13; kt++) {
#pragma unroll
            for (int ks = 0; ks < 2; ks++) {
                int krow = kt * 32 + ks * 16 + lr;
                int swz = (krow & 7) << 4;
                vbf8 b0 = *(const vbf8*)((char*)Kl + ((krow * 128 + q4 * 16) ^ swz));
                vbf8 b1 = *(const vbf8*)((char*)Kl + ((krow * 128 + 64 + q4 * 16) ^ swz));
                vf4 z4 = vf4{0.f, 0.f, 0.f, 0.f};
                vf4 sv = __builtin_amdgcn_mfma_f32_16x16x32_bf16(qs0, b0, z4, 0, 0, 0);
                S[kt][ks] = __builtin_amdgcn_mfma_f32_16x16x32_bf16(qs1, b1, sv, 0, 0, 0);
            }
        }
#pragma unroll
        for (int ks = 0; ks < 2; ks++)
#pragma unroll
            for (int r = 0; r < 4; r++)
                if (ks * 16 + lr >= 4) S[12][ks][r] = -1e30f;

        float mx[4];
#pragma unroll
        for (int r = 0; r < 4; r++) mx[r] = S[0][0][r];
#pragma unroll
        for (int kt = 0; kt < 13; kt++)
#pragma unroll
            for (int ks = 0; ks < 2; ks++)
#pragma unroll
                for (int r = 0; r < 4; r++) mx[r] = fmaxf(mx[r], S[kt][ks][r]);
#pragma unroll
        for (int off = 1; off <= 8; off <<= 1)
#pragma unroll
            for (int r = 0; r < 4; r++) mx[r] = fmaxf(mx[r], __shfl_xor(mx[r], off));

        float l[4] = {0.f, 0.f, 0.f, 0.f};
#pragma unroll
        for (int kt = 0; kt < 13; kt++)
#pragma unroll
            for (int ks = 0; ks < 2; ks++)
#pragma unroll
                for (int r = 0; r < 4; r++) {
                    float p = __expf(S[kt][ks][r] - mx[r]);
                    S[kt][ks][r] = p;
                    l[r] += p;
                }
#pragma unroll
        for (int off = 1; off <= 8; off <<= 1)
#pragma unroll
            for (int r = 0; r < 4; r++) l[r] += __shfl_xor(l[r], off);

        vf4 accO[4];
#pragma unroll
        for (int dc = 0; dc < 4; dc++) accO[dc] = vf4{0.f, 0.f, 0.f, 0.f};
#pragma unroll
        for (int kt = 0; kt < 13; kt++) {
            u16* pw = Pl[w];
#pragma unroll
            for (int ks = 0; ks < 2; ks++)
#pragma unroll
                for (int r = 0; r < 4; r++)
                    pw[(q4 * 4 + r) * 40 + ks * 16 + lr] = f2bf(S[kt][ks][r]);
            vbf8 pf = *(const vbf8*)&Pl[w][lr * 40 + q4 * 8];
#pragma unroll
            for (int dc = 0; dc < 4; dc++) {
                vbf8 vf_ = *(const vbf8*)&Vt[(dc * 16 + lr) * VTS + kt * 32 + q4 * 8];
                accO[dc] = __builtin_amdgcn_mfma_f32_16x16x32_bf16(pf, vf_, accO[dc], 0, 0, 0);
            }
        }

        float invl[4];
#pragma unroll
        for (int r = 0; r < 4; r++) invl[r] = 1.f / l[r];

        vbf8 sq0, sq1;
        float dpart = 0.f;
#pragma unroll
        for (int j = 0; j < 8; j++) {
            float s0 = elu1(bf2f(((u16*)&qf0)[j]));
            float s1 = elu1(bf2f(((u16*)&qf1)[j]));
            ((u16*)&sq0)[j] = f2bf(s0);
            ((u16*)&sq1)[j] = f2bf(s1);
            dpart += s0 * zp[q4 * 8 + j] + s1 * zp[32 + q4 * 8 + j];
        }
        dpart += __shfl_xor(dpart, 16);
        dpart += __shfl_xor(dpart, 32);
        if (q4 == 0) red[w][lr] = dpart;

        vf4 am[4];
#pragma unroll
        for (int dc = 0; dc < 4; dc++) {
            vbf8 b0 = *(const vbf8*)(mtb + (dc * 16 + lr) * 64 + q4 * 8);
            vbf8 b1 = *(const vbf8*)(mtb + (dc * 16 + lr) * 64 + 32 + q4 * 8);
            vf4 z4 = vf4{0.f, 0.f, 0.f, 0.f};
            vf4 a = __builtin_amdgcn_mfma_f32_16x16x32_bf16(sq0, b0, z4, 0, 0, 0);
            am[dc] = __builtin_amdgcn_mfma_f32_16x16x32_bf16(sq1, b1, a, 0, 0, 0);
        }
        float den[4];
#pragma unroll
        for (int r = 0; r < 4; r++) den[r] = 1.f / red[w][q4 * 4 + r];

#pragma unroll
        for (int dc = 0; dc < 4; dc++) {
            float bb = betas[h * D_ + dc * 16 + lr];
            float beta = 1.f / (1.f + __expf(-bb));
#pragma unroll
            for (int r = 0; r < 4; r++) {
                int qs = s * 16 + q4 * 4 + r;
                if (qs < NS) {
                    float o = beta * (am[dc][r] * den[r]) +
                              (1.f - beta) * (accO[dc][r] * invl[r]);
                    concat[((long long)(b * N_ + NT + qs)) * C_ + h * D_ + dc * 16 + lr] = f2bf(o);
                }
            }
        }
    }

    // ---------------- MT strips (rows 0..127, keys 0..127) ----------------
    // wave 1: m=0,7 ; waves 2..7: m=w-1. Wave 0 (3 S-strips) gets none.
    if (w > 0) {
        for (int m = w - 1; m < 8; m += 7) {
            int qtok = m * 16 + lr;
            const u16* qbase = qkv + ((long long)(b * N_ + qtok)) * K3 + h * D_;
            vbf8 qf0 = *(const vbf8*)(qbase + q4 * 8);
            vbf8 qf1 = *(const vbf8*)(qbase + 32 + q4 * 8);
            vbf8 qs0, qs1;
#pragma unroll
            for (int j = 0; j < 8; j++) {
                ((u16*)&qs0)[j] = f2bf(bf2f(((u16*)&qf0)[j]) * 0.125f);
                ((u16*)&qs1)[j] = f2bf(bf2f(((u16*)&qf1)[j]) * 0.125f);
            }

            vf4 S4[4][2];
#pragma unroll
            for (int kt = 0; kt < 4; kt++) {
#pragma unroll
                for (int ks = 0; ks < 2; ks++) {
                    int krow = kt * 32 + ks * 16 + lr;
                    int swz = (krow & 7) << 4;
                    vbf8 b0 = *(const vbf8*)((char*)Kl + ((krow * 128 + q4 * 16) ^ swz));
                    vbf8 b1 = *(const vbf8*)((char*)Kl + ((krow * 128 + 64 + q4 * 16) ^ swz));
                    vf4 z4 = vf4{0.f, 0.f, 0.f, 0.f};
                    vf4 sv = __builtin_amdgcn_mfma_f32_16x16x32_bf16(qs0, b0, z4, 0, 0, 0);
                    S4[kt][ks] = __builtin_amdgcn_mfma_f32_16x16x32_bf16(qs1, b1, sv, 0, 0, 0);
                }
            }

            float mx[4];
#pragma unroll
            for (int r = 0; r < 4; r++) mx[r] = S4[0][0][r];
#pragma unroll
            for (int kt = 0; kt < 4; kt++)
#pragma unroll
                for (int ks = 0; ks < 2; ks++)
#pragma unroll
                    for (int r = 0; r < 4; r++) mx[r] = fmaxf(mx[r], S4[kt][ks][r]);
#pragma unroll
            for (int off = 1; off <= 8; off <<= 1)
#pragma unroll
                for (int r = 0; r < 4; r++) mx[r] = fmaxf(mx[r], __shfl_xor(mx[r], off));

            float l[4] = {0.f, 0.f, 0.f, 0.f};
#pragma unroll
            for (int kt = 0; kt < 4; kt++)
#pragma unroll
                for (int ks = 0; ks < 2; ks++)
#pragma unroll
                    for (int r = 0; r < 4; r++) {
                        float p = __expf(S4[kt][ks][r] - mx[r]);
                        S4[kt][ks][r] = p;
                        l[r] += p;
                    }
#pragma unroll
            for (int off = 1; off <= 8; off <<= 1)
#pragma unroll
                for (int r = 0; r < 4; r++) l[r] += __shfl_xor(l[r], off);

            vf4 accO[4];
#pragma unroll
            for (int dc = 0; dc < 4; dc++) accO[dc] = vf4{0.f, 0.f, 0.f, 0.f};
#pragma unroll
            for (int kt = 0; kt < 4; kt++) {
                u16* pw = Pl[w];
#pragma unroll
                for (int ks = 0; ks < 2; ks++)
#pragma unroll
                    for (int r = 0; r < 4; r++)
                        pw[(q4 * 4 + r) * 40 + ks * 16 + lr] = f2bf(S4[kt][ks][r]);
                vbf8 pf = *(const vbf8*)&Pl[w][lr * 40 + q4 * 8];
#pragma unroll
                for (int dc = 0; dc < 4; dc++) {
                    vbf8 vf_ = *(const vbf8*)&Vt[(dc * 16 + lr) * VTS + kt * 32 + q4 * 8];
                    accO[dc] = __builtin_amdgcn_mfma_f32_16x16x32_bf16(pf, vf_, accO[dc], 0, 0, 0);
                }
            }

            float invl[4];
#pragma unroll
            for (int r = 0; r < 4; r++) invl[r] = 1.f / l[r];

            int qt0 = m * 16;
#pragma unroll
            for (int dc = 0; dc < 4; dc++)
#pragma unroll
                for (int r = 0; r < 4; r++) {
                    int row = qt0 + q4 * 4 + r;
                    concat[((long long)(b * N_ + row)) * C_ + h * D_ + dc * 16 + lr] =
                        f2bf(accO[dc][r] * invl[r]);
                }
        }
    }
}

// ---------------------------------------------------------------------------
// sigma_pred_mem (unchanged from round 11)
// ---------------------------------------------------------------------------
__global__ __launch_bounds__(512) void sigma_pred_mem(
    const u16* __restrict__ ksm, const u16* __restrict__ vsm,
    const u16* __restrict__ memT, const float* __restrict__ zin,
    const float* __restrict__ memin, float* __restrict__ mem_out,
    float* __restrict__ z_out)
{
    __shared__ __align__(16) u16 sigL[64][SPL];
    __shared__ __align__(16) u16 wL[64][SPL];
    __shared__ float red[8][16];
    __shared__ float zpart[8][64];
    __shared__ float zlds[64];

    int bh = blockIdx.x;
    int b = bh / H_, h = bh % H_;
    int t = threadIdx.x, lane = t & 63, w = t >> 6;
    int lr = lane & 15, q4 = lane >> 4;

    if (t < 64) zlds[t] = zin[bh * 64 + t];
    __syncthreads();

    const u16* mtb = memT + (long long)bh * 4096;
    float zacc[16];
#pragma unroll
    for (int j = 0; j < 16; j++) zacc[j] = 0.f;

    for (int s = w; s < 18; s += 8) {
        int n0 = s * 16;
        int nrow = n0 + lr;
        bool vrow = nrow < NS;
        int nclamp = vrow ? nrow : NS - 1;
        const u16* kbase = ksm + ((long long)(b * NS + nclamp)) * C_ + h * D_;
        vbf8 k0 = *(const vbf8*)(kbase + q4 * 8);
        vbf8 k1 = *(const vbf8*)(kbase + 32 + q4 * 8);

        vbf8 sq0, sq1;
        float dpart = 0.f;
#pragma unroll
        for (int j = 0; j < 8; j++) {
            float s0 = vrow ? elu1(bf2f(((u16*)&k0)[j])) : 0.f;
            float s1 = vrow ? elu1(bf2f(((u16*)&k1)[j])) : 0.f;
            u16 b0 = f2bf(s0), b1 = f2bf(s1);
            ((u16*)&sq0)[j] = b0;
            ((u16*)&sq1)[j] = b1;
            zacc[j]     += s0;
            zacc[8 + j] += s1;
            dpart += s0 * zlds[q4 * 8 + j] + s1 * zlds[32 + q4 * 8 + j];
            sigL[q4 * 8 + j][n0 + lr]      = b0;
            sigL[32 + q4 * 8 + j][n0 + lr] = b1;
        }
        dpart += __shfl_xor(dpart, 16);
        dpart += __shfl_xor(dpart, 32);
        if (q4 == 0) red[w][lr] = dpart;

        vf4 am[4];
#pragma unroll
        for (int dc = 0; dc < 4; dc++) {
            vbf8 b0 = *(const vbf8*)(mtb + (dc * 16 + lr) * 64 + q4 * 8);
            vbf8 b1 = *(const vbf8*)(mtb + (dc * 16 + lr) * 64 + 32 + q4 * 8);
            vf4 z4 = vf4{0.f, 0.f, 0.f, 0.f};
            vf4 a = __builtin_amdgcn_mfma_f32_16x16x32_bf16(sq0, b0, z4, 0, 0, 0);
            am[dc] = __builtin_amdgcn_mfma_f32_16x16x32_bf16(sq1, b1, a, 0, 0, 0);
        }
        float rden[4];
#pragma unroll
        for (int r = 0; r < 4; r++) rden[r] = 1.f / red[w][q4 * 4 + r];

#pragma unroll
        for (int dc = 0; dc < 4; dc++) {
            int e = dc * 16 + lr;
#pragma unroll
            for (int r = 0; r < 4; r++) {
                int nn = n0 + q4 * 4 + r;
                float wv = 0.f;
                if (nn < NS) {
                    float pv = am[dc][r] * rden[r];
                    wv = bf2f(vsm[((long long)(b * NS + nn)) * C_ + h * D_ + e]) - pv;
                }
                wL[e][n0 + q4 * 4 + r] = f2bf(wv);
            }
        }
    }

#pragma unroll
    for (int off = 1; off <= 8; off <<= 1)
#pragma unroll
        for (int j = 0; j < 16; j++) zacc[j] += __shfl_xor(zacc[j], off);
    if (lr == 0) {
#pragma unroll
        for (int j = 0; j < 8; j++) {
            zpart[w][q4 * 8 + j]      = zacc[j];
            zpart[w][32 + q4 * 8 + j] = zacc[8 + j];
        }
    }
    __syncthreads();

    if (t < 64) {
        float tot = 0.f;
#pragma unroll
        for (int ww = 0; ww < 8; ww++) tot += zpart[ww][t];
        z_out[bh * 64 + t] = zlds[t] + tot;
    }

    long long mb = (long long)bh * 4096;
#pragma unroll
    for (int p = 0; p < 2; p++) {
        int tid2 = w * 2 + p;
        int i = tid2 >> 2, j = tid2 & 3;
        vf4 acc = vf4{0.f, 0.f, 0.f, 0.f};
#pragma unroll
        for (int kt = 0; kt < SPS; kt += 32) {
            vbf8 af = *(const vbf8*)&sigL[i * 16 + lr][kt + q4 * 8];
            vbf8 bf = *(const vbf8*)&wL[j * 16 + lr][kt + q4 * 8];
            acc = __builtin_amdgcn_mfma_f32_16x16x32_bf16(af, bf, acc, 0, 0, 0);
        }
        int e = j * 16 + lr;
#pragma unroll
        for (int r = 0; r < 4; r++) {
            int dd = i * 16 + q4 * 4 + r;
            mem_out[mb + dd * 64 + e] = memin[mb + dd * 64 + e] + acc[r];
        }
    }
}

// ---------------------------------------------------------------------------
extern "C" void kernel_launch(void* const* d_in, const int* in_sizes, int n_in,
                              void* d_out, int out_size, void* d_ws, size_t ws_size,
                              hipStream_t stream)
{
    const float* x      = (const float*)d_in[0];
    const float* mem    = (const float*)d_in[1];
    const float* z      = (const float*)d_in[2];
    const float* qkv_w  = (const float*)d_in[3];
    const float* qkv_b  = (const float*)d_in[4];
    const float* proj_w = (const float*)d_in[5];
    const float* proj_b = (const float*)d_in[6];
    const float* memk_w = (const float*)d_in[7];
    const float* memk_b = (const float*)d_in[8];
    const float* memv_w = (const float*)d_in[9];
    const float* memv_b = (const float*)d_in[10];
    const float* betas  = (const float*)d_in[11];

    u16* ws     = (u16*)d_ws;
    u16* qkv    = ws;
    u16* ksm    = qkv + QKV_LEN;
    u16* vsm    = ksm + KSM_LEN;
    u16* concat = vsm + KSM_LEN;      // doubles as x_bf before attn writes it

    float* out     = (float*)d_out;
    float* mem_out = out + CAT_LEN;
    float* z_out   = mem_out + MEM_LEN;

    u16* x_bf = concat;               // alias: dead after qkv GEMM
    u16* memT = (u16*)out;            // scratch at d_out base; proj overwrites LAST

    // 0. conversions (merged) + memT
    convert_all<<<dim3(2048 + 1728), dim3(256), 0, stream>>>(
        x, x_bf, qkv_w, memk_w, memv_w, proj_w);
    memT_kernel<<<dim3(B_ * H_), dim3(256), 0, stream>>>(mem, memT);

    // 1. qkv = x @ qkv_w^T + qkv_b   (grid 18 x 388 = 6984, %8 == 0)
    gemm_mfma<0><<<dim3(6984), dim3(256), 0, stream>>>(
        x_bf, 0ll, 49664, 0ll, 768ll, WOFF_QKV, qkv_b, qkv, K3, 18);
    // 2+3. k_s_mem and v_s_mem in one dual launch (2 x 1560 blocks)
    gemm_mfma_dual<<<dim3(3120), dim3(256), 0, stream>>>(
        qkv, (long long)(NT * K3 + C_), (long long)(NT * K3 + 2 * C_),
        NS, (long long)N_ * K3, (long long)K3,
        WOFF_MEMK, WOFF_MEMV, memk_b, memv_b, ksm, vsm, C_, 6, 1560);
    // 4+5. fused spatial + token attention -> concat
    attn_fused<<<dim3(B_ * H_), dim3(512), 0, stream>>>(
        qkv, memT, z, betas, concat);
    // 6+7. fused sigma/pred + z_new + mem_new
    sigma_pred_mem<<<dim3(B_ * H_), dim3(512), 0, stream>>>(
        ksm, vsm, memT, z, mem, mem_out, z_out);
    // 8. out = concat @ proj_w^T + proj_b   (grid 6 x 388 = 2328; overwrites memT)
    gemm_mfma<1><<<dim3(2328), dim3(256), 0, stream>>>(
        concat, 0ll, 49664, 0ll, 768ll, WOFF_PROJ, proj_b, out, C_, 6);
}